// Round 1
// baseline (4514.008 us; speedup 1.0000x reference)
//
#include <hip/hip_runtime.h>

// LTV Kalman filter, restructured for GPU:
//  K0: scalars (sigma_max power iter, A=alpha*I detect, sum log r_e, Q)
//  K1: per-t Woodbury precompute S,G,H (bf16), b,c,activeN  (parallel over t)
//  K2 x NSWEEPS: Jacobi sweeps of the Riccati recursion (parallel over t,
//      contraction ~0.35/step -> 10 sweeps converge), Gauss-Jordan 64x64
//      in-place inverse gives M^-1 and logdet. Last sweep stores W=M^-1(bf16),
//      logdet.
//  K3: state + loglik pass, chunked parallel with 48-step warmup (recursion
//      forgets: ||a(I-WG)|| ~ 0.6).

#define TT 2048
#define NN 256
#define KKD 64
#define PIT 68           // LDS pitch (floats/ushorts), multiple of 4, bank-shifted
#define NSWEEPS 10
#define LOG2PI 1.8378770664093453f

typedef unsigned short u16;
typedef unsigned int u32;

__device__ __forceinline__ float bf2f(u16 u) {
  u32 x = ((u32)u) << 16;
  return __uint_as_float(x);
}
__device__ __forceinline__ u16 f2bf(float f) {
  u32 u = __float_as_uint(f);
  u32 r = (u + 0x7fffu + ((u >> 16) & 1u)) >> 16;
  return (u16)r;
}
__device__ __forceinline__ u32 pack2(float a, float b) {
  return (u32)f2bf(a) | ((u32)f2bf(b) << 16);
}
__device__ __forceinline__ float4 ldF4(const float* p) { return *(const float4*)p; }

// ---------------- K0: scalars ----------------
__global__ __launch_bounds__(256) void k0(const float* __restrict__ Araw,
                                          const float* __restrict__ logQ,
                                          const float* __restrict__ logR,
                                          float* hdr, float* Qd, float* Asc) {
  __shared__ float Bm[64 * PIT];
  __shared__ float red[256];
  __shared__ float vv[64];
  int tid = threadIdx.x;
  if (tid < 64) Qd[tid] = expf(logQ[tid]);
  // sum log(r + 1e-4)
  float r = expf(logR[tid]);
  red[tid] = logf(r + 1e-4f);
  __syncthreads();
  for (int o = 128; o; o >>= 1) {
    if (tid < o) red[tid] += red[tid + o];
    __syncthreads();
  }
  if (tid == 0) hdr[2] = red[0];
  __syncthreads();
  // detect A = alpha*I (binary exact on provided inputs)
  float a0 = Araw[0];
  float okf = 1.0f;
  for (int u = 0; u < 16; ++u) {
    int idx = tid * 16 + u;
    int i = idx >> 6, j = idx & 63;
    float v = Araw[idx];
    bool good = (i == j) ? (v == a0) : (v == 0.0f);
    if (!good) okf = 0.0f;
  }
  red[tid] = okf;
  __syncthreads();
  for (int o = 128; o; o >>= 1) {
    if (tid < o) red[tid] = fminf(red[tid], red[tid + o]);
    __syncthreads();
  }
  float isDiag = red[0];
  __syncthreads();
  // B = A^T A
  for (int u = 0; u < 16; ++u) {
    int idx = tid * 16 + u;
    int i = idx >> 6, j = idx & 63;
    float s = 0.f;
    for (int k = 0; k < 64; ++k) s += Araw[k * 64 + i] * Araw[k * 64 + j];
    Bm[i * PIT + j] = s;
  }
  __syncthreads();
  // power iteration for sigma_max = sqrt(lambda_max(A^T A))
  if (tid < 64) {
    vv[tid] = 1.0f;
    float lam = 0.f;
    for (int it = 0; it < 64; ++it) {
      float ui = 0.f;
      for (int k = 0; k < 64; ++k) ui += Bm[tid * PIT + k] * vv[k];
      float s = ui * ui;
      for (int o = 32; o; o >>= 1) s += __shfl_down(s, o);
      float n2 = __shfl(s, 0);
      float nr = sqrtf(fmaxf(n2, 1e-30f));
      vv[tid] = ui / nr;
      lam = nr;
    }
    if (tid == 0) red[0] = lam;
  }
  __syncthreads();
  float sig = sqrtf(fmaxf(red[0], 0.f));
  float scale = 0.98f / (sig + 1e-6f);
  if (tid == 0) {
    hdr[0] = scale * a0;  // scalar a (valid when diag)
    hdr[1] = isDiag;
    hdr[3] = sig;
  }
  for (int u = 0; u < 16; ++u) {
    int idx = tid * 16 + u;
    Asc[idx] = scale * Araw[idx];
  }
}

// ---------------- K1: per-t Woodbury precompute ----------------
__global__ __launch_bounds__(256) void k1(const float* __restrict__ obs,
                                          const float* __restrict__ Lam,
                                          const float* __restrict__ logR,
                                          u16* __restrict__ Sg, u16* __restrict__ Gg,
                                          u16* __restrict__ Hg, float* __restrict__ bv,
                                          float* __restrict__ cv, float* __restrict__ aNv) {
  int t = blockIdx.x, tid = threadIdx.x;
  __shared__ float Lt[NN * PIT];
  __shared__ float w1a[NN], w2a[NN], w3a[NN], wya[NN];
  __shared__ float red[NN];
  // per-observation weights
  float y = obs[(size_t)t * NN + tid];
  float r = expf(logR[tid]);
  float re = r + 1e-4f;
  float w1 = 1.0f / re;
  bool m = (y != y);  // isnan
  float w2 = m ? 0.f : w1;
  float w3 = m ? 0.f : r / (re * re);
  w1a[tid] = w1;
  w2a[tid] = w2;
  w3a[tid] = w3;
  wya[tid] = m ? 0.f : (w1 * y);
  float cpart = m ? 0.f : (w1 * y * y);
  float apart = m ? 0.f : 1.f;
  // stage L tile
  const float4* Lsrc = (const float4*)(Lam + (size_t)t * NN * KKD);
  for (int u = 0; u < 16; ++u) {
    int fl = u * 256 + tid;
    float4 v = Lsrc[fl];
    int n = fl >> 4, c4 = (fl & 15) * 4;
    *(float4*)&Lt[n * PIT + c4] = v;
  }
  __syncthreads();
  int ig = tid >> 4, jg = tid & 15;
  int i0 = ig * 4, j0 = jg * 4;
  float s_[4][4] = {}, g_[4][4] = {}, h_[4][4] = {};
  for (int n = 0; n < NN; ++n) {
    float4 la = ldF4(&Lt[n * PIT + i0]);
    float4 lb = ldF4(&Lt[n * PIT + j0]);
    float W1 = w1a[n], W2 = w2a[n], W3 = w3a[n];
    float A_[4] = {la.x, la.y, la.z, la.w};
    float B_[4] = {lb.x, lb.y, lb.z, lb.w};
#pragma unroll
    for (int a = 0; a < 4; ++a)
#pragma unroll
      for (int b = 0; b < 4; ++b) {
        float p = A_[a] * B_[b];
        s_[a][b] = fmaf(W1, p, s_[a][b]);
        g_[a][b] = fmaf(W2, p, g_[a][b]);
        h_[a][b] = fmaf(W3, p, h_[a][b]);
      }
  }
  size_t base = (size_t)t * 4096;
#pragma unroll
  for (int a = 0; a < 4; ++a) {
    int row = i0 + a;
    ushort4 us;
    us.x = f2bf(s_[a][0]); us.y = f2bf(s_[a][1]); us.z = f2bf(s_[a][2]); us.w = f2bf(s_[a][3]);
    *(ushort4*)&Sg[base + row * 64 + j0] = us;
    us.x = f2bf(g_[a][0]); us.y = f2bf(g_[a][1]); us.z = f2bf(g_[a][2]); us.w = f2bf(g_[a][3]);
    *(ushort4*)&Gg[base + row * 64 + j0] = us;
    us.x = f2bf(h_[a][0]); us.y = f2bf(h_[a][1]); us.z = f2bf(h_[a][2]); us.w = f2bf(h_[a][3]);
    *(ushort4*)&Hg[base + row * 64 + j0] = us;
  }
  // b = sum w1*y*l (unmasked)
  if (tid < 64) {
    float acc = 0.f;
    for (int n = 0; n < NN; ++n) acc += wya[n] * Lt[n * PIT + tid];
    bv[(size_t)t * 64 + tid] = acc;
  }
  // c, activeN reductions
  red[tid] = cpart;
  __syncthreads();
  for (int o = 128; o; o >>= 1) {
    if (tid < o) red[tid] += red[tid + o];
    __syncthreads();
  }
  if (tid == 0) cv[t] = red[0];
  __syncthreads();
  red[tid] = apart;
  __syncthreads();
  for (int o = 128; o; o >>= 1) {
    if (tid < o) red[tid] += red[tid + o];
    __syncthreads();
  }
  if (tid == 0) aNv[t] = red[0];
}

// ---------------- K2: one Jacobi sweep of the Riccati recursion ----------------
// Matmul tile: each of 512 threads computes a 2x4 tile; all products are
// row(A) dot row(B) (B symmetric, or we want B^T).
template <int AT, int BT>
__device__ __forceinline__ void mmTile(float acc[2][4], const float* Albs,
                                       const float* Aglb, const float* Bf,
                                       const u16* Bh, const float* Bg, int i0, int j0) {
#pragma unroll
  for (int k = 0; k < 64; k += 4) {
    float4 a0, a1;
    if (AT == 0) {
      a0 = ldF4(&Albs[i0 * PIT + k]);
      a1 = ldF4(&Albs[(i0 + 1) * PIT + k]);
    } else {
      a0 = ldF4(&Aglb[i0 * 64 + k]);
      a1 = ldF4(&Aglb[(i0 + 1) * 64 + k]);
    }
#pragma unroll
    for (int c = 0; c < 4; ++c) {
      float4 b;
      if (BT == 0)
        b = ldF4(&Bf[(j0 + c) * PIT + k]);
      else if (BT == 1) {
        ushort4 u = *(const ushort4*)&Bh[(j0 + c) * PIT + k];
        b = make_float4(bf2f(u.x), bf2f(u.y), bf2f(u.z), bf2f(u.w));
      } else
        b = ldF4(&Bg[(j0 + c) * 64 + k]);
      acc[0][c] = fmaf(a0.x, b.x, fmaf(a0.y, b.y, fmaf(a0.z, b.z, fmaf(a0.w, b.w, acc[0][c]))));
      acc[1][c] = fmaf(a1.x, b.x, fmaf(a1.y, b.y, fmaf(a1.z, b.z, fmaf(a1.w, b.w, acc[1][c]))));
    }
  }
}

__device__ __forceinline__ void stageB(const u16* __restrict__ src, u16* Bst, int tid) {
  uint4 raw = *(const uint4*)(src + tid * 8);
  int row = tid >> 3, col = (tid & 7) * 8;
  ushort4 lo, hi;
  lo.x = (u16)(raw.x & 0xffff); lo.y = (u16)(raw.x >> 16);
  lo.z = (u16)(raw.y & 0xffff); lo.w = (u16)(raw.y >> 16);
  hi.x = (u16)(raw.z & 0xffff); hi.y = (u16)(raw.z >> 16);
  hi.z = (u16)(raw.w & 0xffff); hi.w = (u16)(raw.w >> 16);
  *(ushort4*)&Bst[row * PIT + col] = lo;
  *(ushort4*)&Bst[row * PIT + col + 4] = hi;
}

__global__ __launch_bounds__(512) void k2(const u16* __restrict__ Sg, const u16* __restrict__ Gg,
                                          const u16* __restrict__ Hg, const u16* __restrict__ Pin,
                                          u16* __restrict__ Pout, u16* __restrict__ Wout,
                                          float* __restrict__ ldv, const float* __restrict__ hdr,
                                          const float* __restrict__ Qd, const float* __restrict__ Asc,
                                          int sweep, int last) {
  int t = blockIdx.x, tid = threadIdx.x;
  __shared__ float Pm[64 * PIT], Wm[64 * PIT], TA[64 * PIT], T1[64 * PIT];
  __shared__ u16 Bst[64 * PIT];
  __shared__ float sc[4];
  int ig = tid >> 4, jg = tid & 15;
  int i0 = 2 * ig, j0 = 4 * jg;
  int row8 = tid >> 3, col8 = (tid & 7) * 8;
  float aS = hdr[0];
  bool diag = (hdr[1] != 0.f);
  float acc[2][4];

  // 1. load P_prev (posterior at t-1)
  if (t == 0) {
    for (int u = 0; u < 8; ++u) {
      int c = col8 + u;
      Pm[row8 * PIT + c] = (row8 == c) ? 1.f : 0.f;
    }
  } else if (sweep == 0) {
    for (int u = 0; u < 8; ++u) {
      int c = col8 + u;
      Pm[row8 * PIT + c] = (row8 == c) ? 0.15f : 0.f;
    }
  } else {
    uint4 raw = *(const uint4*)(Pin + (size_t)(t - 1) * 4096 + tid * 8);
    float4 lo = make_float4(bf2f((u16)(raw.x & 0xffff)), bf2f((u16)(raw.x >> 16)),
                            bf2f((u16)(raw.y & 0xffff)), bf2f((u16)(raw.y >> 16)));
    float4 hi = make_float4(bf2f((u16)(raw.z & 0xffff)), bf2f((u16)(raw.z >> 16)),
                            bf2f((u16)(raw.w & 0xffff)), bf2f((u16)(raw.w >> 16)));
    *(float4*)&Pm[row8 * PIT + col8] = lo;
    *(float4*)&Pm[row8 * PIT + col8 + 4] = hi;
  }
  __syncthreads();

  // 2. P_pred = A P A^T + Q
  if (diag) {
    float a2 = aS * aS;
    int base = row8 * PIT + col8;
    for (int u = 0; u < 8; ++u) {
      float x = Pm[base + u] * a2;
      if (col8 + u == row8) x += Qd[row8];
      Pm[base + u] = x;
    }
    __syncthreads();
  } else {
    for (int c = 0; c < 4; ++c) acc[0][c] = acc[1][c] = 0.f;
    mmTile<1, 0>(acc, nullptr, Asc, Pm, nullptr, nullptr, i0, j0);  // tmp = A*P
#pragma unroll
    for (int rr = 0; rr < 2; ++rr)
      *(float4*)&TA[(i0 + rr) * PIT + j0] =
          make_float4(acc[rr][0], acc[rr][1], acc[rr][2], acc[rr][3]);
    __syncthreads();
    for (int c = 0; c < 4; ++c) acc[0][c] = acc[1][c] = 0.f;
    mmTile<0, 2>(acc, TA, nullptr, nullptr, nullptr, Asc, i0, j0);  // tmp*A^T
    __syncthreads();
#pragma unroll
    for (int rr = 0; rr < 2; ++rr)
#pragma unroll
      for (int c = 0; c < 4; ++c) {
        int I = i0 + rr, J = j0 + c;
        float v = acc[rr][c];
        if (I == J) v += Qd[I];
        Pm[I * PIT + J] = v;
      }
    __syncthreads();
  }

  // 3-4. Mt = I + P_pred * S
  stageB(Sg + (size_t)t * 4096, Bst, tid);
  __syncthreads();
  for (int c = 0; c < 4; ++c) acc[0][c] = acc[1][c] = 0.f;
  mmTile<0, 1>(acc, Pm, nullptr, nullptr, Bst, nullptr, i0, j0);
#pragma unroll
  for (int rr = 0; rr < 2; ++rr)
#pragma unroll
    for (int c = 0; c < 4; ++c) {
      int I = i0 + rr, J = j0 + c;
      TA[I * PIT + J] = acc[rr][c] + ((I == J) ? 1.f : 0.f);
    }
  __syncthreads();

  // 5. in-place Gauss-Jordan inverse of TA, logdet from pivots
  float ldacc = 0.f;
  for (int j = 0; j < 64; ++j) {
    float piv = TA[j * PIT + j];
    float f0 = TA[i0 * PIT + j];
    float f1 = TA[(i0 + 1) * PIT + j];
    float4 pr4 = ldF4(&TA[j * PIT + j0]);
    __syncthreads();
    float ap = fabsf(piv);
    float pv = (ap < 1e-30f) ? ((piv < 0.f) ? -1e-30f : 1e-30f) : piv;
    float pr = 1.0f / pv;
    if (tid == 0) ldacc += logf(fabsf(pv));
    float pj[4] = {pr4.x, pr4.y, pr4.z, pr4.w};
#pragma unroll
    for (int rr = 0; rr < 2; ++rr) {
      int i = i0 + rr;
      float f = rr ? f1 : f0;
      float4 cur = ldF4(&TA[i * PIT + j0]);
      float cu[4] = {cur.x, cur.y, cur.z, cur.w};
      float o[4];
#pragma unroll
      for (int c = 0; c < 4; ++c) {
        int k = j0 + c;
        float v;
        if (i == j)
          v = (k == j) ? pr : pj[c] * pr;
        else if (k == j)
          v = -f * pr;
        else
          v = cu[c] - f * pr * pj[c];
        o[c] = v;
      }
      *(float4*)&TA[i * PIT + j0] = make_float4(o[0], o[1], o[2], o[3]);
    }
    __syncthreads();
  }
  if (tid == 0) sc[0] = ldacc;

  // 6. W = X * P_pred  (= (P^-1 + S)^-1)
  for (int c = 0; c < 4; ++c) acc[0][c] = acc[1][c] = 0.f;
  mmTile<0, 0>(acc, TA, nullptr, Pm, nullptr, nullptr, i0, j0);
#pragma unroll
  for (int rr = 0; rr < 2; ++rr)
    *(float4*)&Wm[(i0 + rr) * PIT + j0] =
        make_float4(acc[rr][0], acc[rr][1], acc[rr][2], acc[rr][3]);
  __syncthreads();

  // 7-8. E = I - W*G
  stageB(Gg + (size_t)t * 4096, Bst, tid);
  __syncthreads();
  for (int c = 0; c < 4; ++c) acc[0][c] = acc[1][c] = 0.f;
  mmTile<0, 1>(acc, Wm, nullptr, nullptr, Bst, nullptr, i0, j0);
#pragma unroll
  for (int rr = 0; rr < 2; ++rr)
#pragma unroll
    for (int c = 0; c < 4; ++c) {
      int I = i0 + rr, J = j0 + c;
      T1[I * PIT + J] = ((I == J) ? 1.f : 0.f) - acc[rr][c];
    }
  __syncthreads();

  // 9-10. Z = W*H
  stageB(Hg + (size_t)t * 4096, Bst, tid);
  __syncthreads();
  for (int c = 0; c < 4; ++c) acc[0][c] = acc[1][c] = 0.f;
  mmTile<0, 1>(acc, Wm, nullptr, nullptr, Bst, nullptr, i0, j0);
#pragma unroll
  for (int rr = 0; rr < 2; ++rr)
    *(float4*)&TA[(i0 + rr) * PIT + j0] =
        make_float4(acc[rr][0], acc[rr][1], acc[rr][2], acc[rr][3]);
  __syncthreads();

  // 11. C2 = Z*W  (in place over TA: compute -> barrier -> write)
  for (int c = 0; c < 4; ++c) acc[0][c] = acc[1][c] = 0.f;
  mmTile<0, 0>(acc, TA, nullptr, Wm, nullptr, nullptr, i0, j0);
  __syncthreads();
#pragma unroll
  for (int rr = 0; rr < 2; ++rr)
    *(float4*)&TA[(i0 + rr) * PIT + j0] =
        make_float4(acc[rr][0], acc[rr][1], acc[rr][2], acc[rr][3]);
  __syncthreads();

  // 12. Y = E*P_pred  -> Pm
  for (int c = 0; c < 4; ++c) acc[0][c] = acc[1][c] = 0.f;
  mmTile<0, 0>(acc, T1, nullptr, Pm, nullptr, nullptr, i0, j0);
  __syncthreads();
#pragma unroll
  for (int rr = 0; rr < 2; ++rr)
    *(float4*)&Pm[(i0 + rr) * PIT + j0] =
        make_float4(acc[rr][0], acc[rr][1], acc[rr][2], acc[rr][3]);
  __syncthreads();

  // 13. P_upd = Y*E^T + C2 -> Pm
  for (int c = 0; c < 4; ++c) acc[0][c] = acc[1][c] = 0.f;
  mmTile<0, 0>(acc, Pm, nullptr, T1, nullptr, nullptr, i0, j0);
  __syncthreads();
#pragma unroll
  for (int rr = 0; rr < 2; ++rr)
#pragma unroll
    for (int c = 0; c < 4; ++c) {
      int I = i0 + rr, J = j0 + c;
      Pm[I * PIT + J] = acc[rr][c] + TA[I * PIT + J];
    }
  __syncthreads();

  // 14. symmetrize
  float vs[8];
  for (int u = 0; u < 8; ++u) {
    int c = col8 + u;
    vs[u] = 0.5f * (Pm[row8 * PIT + c] + Pm[c * PIT + row8]);
  }
  __syncthreads();
  for (int u = 0; u < 8; ++u) Pm[row8 * PIT + col8 + u] = vs[u];
  __syncthreads();

  // 15. store
  {
    int base = row8 * PIT + col8;
    uint4 o;
    o.x = pack2(Pm[base + 0], Pm[base + 1]);
    o.y = pack2(Pm[base + 2], Pm[base + 3]);
    o.z = pack2(Pm[base + 4], Pm[base + 5]);
    o.w = pack2(Pm[base + 6], Pm[base + 7]);
    *(uint4*)(Pout + (size_t)t * 4096 + tid * 8) = o;
    if (last) {
      uint4 w;
      w.x = pack2(Wm[base + 0], Wm[base + 1]);
      w.y = pack2(Wm[base + 2], Wm[base + 3]);
      w.z = pack2(Wm[base + 4], Wm[base + 5]);
      w.w = pack2(Wm[base + 6], Wm[base + 7]);
      *(uint4*)(Wout + (size_t)t * 4096 + tid * 8) = w;
      if (tid == 0) ldv[t] = sc[0];
    }
  }
}

// ---------------- K3: state + loglik, chunked parallel with warmup ----------------
#define OWN 16
#define WARM 48
__global__ __launch_bounds__(256) void k3(const u16* __restrict__ Gg, const u16* __restrict__ Wg,
                                          const float* __restrict__ bv, const float* __restrict__ cv,
                                          const float* __restrict__ aNv, const float* __restrict__ ldv,
                                          const float* __restrict__ hdr, const float* __restrict__ Asc,
                                          float* __restrict__ out) {
  int b = blockIdx.x, tid = threadIdx.x;
  int t0 = b * OWN;
  int tw = t0 - WARM;
  if (tw < 0) tw = 0;
  __shared__ float z[64], zp[64], q[64], wv[64], uu[64], part[256];
  float aS = hdr[0];
  bool diag = (hdr[1] != 0.f);
  float slr = hdr[2];
  if (tid < 64) z[tid] = 0.f;
  __syncthreads();
  for (int t = tw; t < t0 + OWN; ++t) {
    bool own = (t >= t0);
    // z_pred
    if (tid < 64) {
      if (diag)
        zp[tid] = aS * z[tid];
      else {
        float s = 0.f;
        for (int k = 0; k < 64; k += 4) {
          float4 a = ldF4(&Asc[tid * 64 + k]);
          s += a.x * z[k] + a.y * z[k + 1] + a.z * z[k + 2] + a.w * z[k + 3];
        }
        zp[tid] = s;
      }
    }
    __syncthreads();
    // q = G * zp
    {
      int i = tid & 63, seg = tid >> 6;
      const u16* Gr = Gg + (size_t)t * 4096 + i * 64 + seg * 16;
      float s = 0.f;
      for (int u = 0; u < 16; u += 4) {
        ushort4 g4 = *(const ushort4*)(Gr + u);
        const float* zz = &zp[seg * 16 + u];
        s += bf2f(g4.x) * zz[0] + bf2f(g4.y) * zz[1] + bf2f(g4.z) * zz[2] + bf2f(g4.w) * zz[3];
      }
      part[tid] = s;
    }
    __syncthreads();
    if (tid < 64) {
      float qi = part[tid] + part[tid + 64] + part[tid + 128] + part[tid + 192];
      q[tid] = qi;
      wv[tid] = bv[(size_t)t * 64 + tid] - qi;
    }
    __syncthreads();
    // u = W * wv
    {
      int i = tid & 63, seg = tid >> 6;
      const u16* Wr = Wg + (size_t)t * 4096 + i * 64 + seg * 16;
      float s = 0.f;
      for (int u = 0; u < 16; u += 4) {
        ushort4 g4 = *(const ushort4*)(Wr + u);
        const float* zz = &wv[seg * 16 + u];
        s += bf2f(g4.x) * zz[0] + bf2f(g4.y) * zz[1] + bf2f(g4.z) * zz[2] + bf2f(g4.w) * zz[3];
      }
      part[tid] = s;
    }
    __syncthreads();
    if (tid < 64) {
      float ui = part[tid] + part[tid + 64] + part[tid + 128] + part[tid + 192];
      uu[tid] = ui;
      z[tid] = zp[tid] + ui;
    }
    __syncthreads();
    if (tid < 64) {
      float bz = bv[(size_t)t * 64 + tid] * zp[tid];
      float zq = zp[tid] * q[tid];
      float wu = wv[tid] * uu[tid];
      for (int o = 32; o; o >>= 1) {
        bz += __shfl_down(bz, o);
        zq += __shfl_down(zq, o);
        wu += __shfl_down(wu, o);
      }
      if (tid == 0 && own) {
        float mahal = cv[t] - 2.f * bz + zq - wu;
        float ll = -0.5f * (aNv[t] * LOG2PI + slr + ldv[t] + mahal);
        if (!isfinite(ll)) ll = -1e6f;
        out[(size_t)t * 65 + 64] = ll;
      }
      if (own) out[(size_t)t * 65 + tid] = z[tid];
    }
    __syncthreads();
  }
}

extern "C" void kernel_launch(void* const* d_in, const int* in_sizes, int n_in,
                              void* d_out, int out_size, void* d_ws, size_t ws_size,
                              hipStream_t stream) {
  const float* obs = (const float*)d_in[0];
  const float* Lam = (const float*)d_in[1];
  const float* Araw = (const float*)d_in[2];
  const float* logQ = (const float*)d_in[3];
  const float* logR = (const float*)d_in[4];
  float* out = (float*)d_out;

  char* w = (char*)d_ws;
  float* hdr = (float*)w;
  float* Qd = hdr + 64;
  float* Asc = hdr + 128;
  const size_t MB = (size_t)TT * 4096;
  u16* Sg = (u16*)(w + 32768);
  u16* Gg = Sg + MB;
  u16* Hg = Gg + MB;
  u16* Wg = Hg + MB;
  u16* Pb0 = Wg + MB;
  u16* Pb1 = Pb0 + MB;
  float* bv = (float*)(Pb1 + MB);
  float* cv = bv + (size_t)TT * 64;
  float* aNv = cv + TT;
  float* ldv = aNv + TT;

  k0<<<dim3(1), dim3(256), 0, stream>>>(Araw, logQ, logR, hdr, Qd, Asc);
  k1<<<dim3(TT), dim3(256), 0, stream>>>(obs, Lam, logR, Sg, Gg, Hg, bv, cv, aNv);
  for (int s = 0; s < NSWEEPS; ++s) {
    const u16* pin = (s & 1) ? Pb1 : Pb0;
    u16* pout = (s & 1) ? Pb0 : Pb1;
    k2<<<dim3(TT), dim3(512), 0, stream>>>(Sg, Gg, Hg, pin, pout, Wg, ldv, hdr, Qd, Asc, s,
                                           (s == NSWEEPS - 1) ? 1 : 0);
  }
  k3<<<dim3(TT / OWN), dim3(256), 0, stream>>>(Gg, Wg, bv, cv, aNv, ldv, hdr, Asc, out);
}

// Round 3
// 1958.664 us; speedup vs baseline: 2.3046x; 2.3046x over previous
//
#include <hip/hip_runtime.h>

// LTV Kalman filter, GPU-restructured (Woodbury + parallel Jacobi-Riccati).
// R3: MFMA matmuls kept; Gauss-Jordan reverted to R1-proven scalar version;
// non-finite scrubbing at all global stores to prevent NaN cascades.

#define TT 2048
#define NN 256
#define KKD 64
#define PIT 68      // fp32 LDS pitch
#define PB 72       // bf16 LDS pitch (rows 16B-aligned)
#define NSWEEPS 8
#define LOG2PI 1.8378770664093453f

typedef unsigned short u16;
typedef unsigned int u32;
typedef __attribute__((ext_vector_type(8))) short short8;
typedef __attribute__((ext_vector_type(4))) float f32x4;

__device__ __forceinline__ float bf2f(u16 u) {
  u32 x = ((u32)u) << 16;
  return __uint_as_float(x);
}
__device__ __forceinline__ u16 f2bf(float f) {
  u32 u = __float_as_uint(f);
  u32 r = (u + 0x7fffu + ((u >> 16) & 1u)) >> 16;
  return (u16)r;
}
__device__ __forceinline__ u32 pack2(float a, float b) {
  return (u32)f2bf(a) | ((u32)f2bf(b) << 16);
}
__device__ __forceinline__ float4 ldF4(const float* p) { return *(const float4*)p; }
__device__ __forceinline__ float fin(float v) { return isfinite(v) ? v : 0.f; }

// ---------------- K0: scalars ----------------
__global__ __launch_bounds__(256) void k0(const float* __restrict__ Araw,
                                          const float* __restrict__ logQ,
                                          const float* __restrict__ logR,
                                          float* hdr, float* Qd, float* Asc, u16* Ab16) {
  __shared__ __align__(16) float Bm[64 * PIT];
  __shared__ __align__(16) float red[256];
  __shared__ __align__(16) float vv[64];
  int tid = threadIdx.x;
  if (tid < 64) Qd[tid] = expf(logQ[tid]);
  float r = expf(logR[tid]);
  red[tid] = logf(r + 1e-4f);
  __syncthreads();
  for (int o = 128; o; o >>= 1) {
    if (tid < o) red[tid] += red[tid + o];
    __syncthreads();
  }
  if (tid == 0) hdr[2] = red[0];
  __syncthreads();
  float a0 = Araw[0];
  float okf = 1.0f;
  for (int u = 0; u < 16; ++u) {
    int idx = tid * 16 + u;
    int i = idx >> 6, j = idx & 63;
    float v = Araw[idx];
    bool good = (i == j) ? (v == a0) : (v == 0.0f);
    if (!good) okf = 0.0f;
  }
  red[tid] = okf;
  __syncthreads();
  for (int o = 128; o; o >>= 1) {
    if (tid < o) red[tid] = fminf(red[tid], red[tid + o]);
    __syncthreads();
  }
  float isDiag = red[0];
  __syncthreads();
  for (int u = 0; u < 16; ++u) {
    int idx = tid * 16 + u;
    int i = idx >> 6, j = idx & 63;
    float s = 0.f;
    for (int k = 0; k < 64; ++k) s += Araw[k * 64 + i] * Araw[k * 64 + j];
    Bm[i * PIT + j] = s;
  }
  __syncthreads();
  if (tid < 64) {
    vv[tid] = 1.0f;
    float lam = 0.f;
    for (int it = 0; it < 64; ++it) {
      float ui = 0.f;
      for (int k = 0; k < 64; ++k) ui += Bm[tid * PIT + k] * vv[k];
      float s = ui * ui;
      for (int o = 32; o; o >>= 1) s += __shfl_down(s, o);
      float n2 = __shfl(s, 0);
      float nr = sqrtf(fmaxf(n2, 1e-30f));
      vv[tid] = ui / nr;
      lam = nr;
    }
    if (tid == 0) red[0] = lam;
  }
  __syncthreads();
  float sig = sqrtf(fmaxf(red[0], 0.f));
  float scale = 0.98f / (sig + 1e-6f);
  if (tid == 0) {
    hdr[0] = scale * a0;
    hdr[1] = isDiag;
    hdr[3] = sig;
  }
  for (int u = 0; u < 16; ++u) {
    int idx = tid * 16 + u;
    float v = scale * Araw[idx];
    Asc[idx] = v;
    Ab16[idx] = f2bf(v);
  }
}

// ---------------- K1: per-t Woodbury precompute ----------------
__global__ __launch_bounds__(256) void k1(const float* __restrict__ obs,
                                          const float* __restrict__ Lam,
                                          const float* __restrict__ logR,
                                          u16* __restrict__ Sg, u16* __restrict__ Gg,
                                          u16* __restrict__ Hg, float* __restrict__ bv,
                                          float* __restrict__ cv, float* __restrict__ aNv) {
  int t = blockIdx.x, tid = threadIdx.x;
  __shared__ __align__(16) float Lt[NN * PIT];
  __shared__ __align__(16) float w1a[NN], w2a[NN], w3a[NN], wya[NN];
  __shared__ __align__(16) float red[NN];
  float y = obs[(size_t)t * NN + tid];
  float r = expf(logR[tid]);
  float re = r + 1e-4f;
  float w1 = 1.0f / re;
  bool m = (y != y);
  float w2 = m ? 0.f : w1;
  float w3 = m ? 0.f : r / (re * re);
  w1a[tid] = w1;
  w2a[tid] = w2;
  w3a[tid] = w3;
  wya[tid] = m ? 0.f : (w1 * y);
  float cpart = m ? 0.f : (w1 * y * y);
  float apart = m ? 0.f : 1.f;
  const float4* Lsrc = (const float4*)(Lam + (size_t)t * NN * KKD);
  for (int u = 0; u < 16; ++u) {
    int fl = u * 256 + tid;
    float4 v = Lsrc[fl];
    int n = fl >> 4, c4 = (fl & 15) * 4;
    *(float4*)&Lt[n * PIT + c4] = v;
  }
  __syncthreads();
  int ig = tid >> 4, jg = tid & 15;
  int i0 = ig * 4, j0 = jg * 4;
  float s_[4][4] = {}, g_[4][4] = {}, h_[4][4] = {};
  for (int n = 0; n < NN; ++n) {
    float4 la = ldF4(&Lt[n * PIT + i0]);
    float4 lb = ldF4(&Lt[n * PIT + j0]);
    float W1 = w1a[n], W2 = w2a[n], W3 = w3a[n];
    float A_[4] = {la.x, la.y, la.z, la.w};
    float B_[4] = {lb.x, lb.y, lb.z, lb.w};
#pragma unroll
    for (int a = 0; a < 4; ++a)
#pragma unroll
      for (int b = 0; b < 4; ++b) {
        float p = A_[a] * B_[b];
        s_[a][b] = fmaf(W1, p, s_[a][b]);
        g_[a][b] = fmaf(W2, p, g_[a][b]);
        h_[a][b] = fmaf(W3, p, h_[a][b]);
      }
  }
  size_t base = (size_t)t * 4096;
#pragma unroll
  for (int a = 0; a < 4; ++a) {
    int row = i0 + a;
    ushort4 us;
    us.x = f2bf(s_[a][0]); us.y = f2bf(s_[a][1]); us.z = f2bf(s_[a][2]); us.w = f2bf(s_[a][3]);
    *(ushort4*)&Sg[base + row * 64 + j0] = us;
    us.x = f2bf(g_[a][0]); us.y = f2bf(g_[a][1]); us.z = f2bf(g_[a][2]); us.w = f2bf(g_[a][3]);
    *(ushort4*)&Gg[base + row * 64 + j0] = us;
    us.x = f2bf(h_[a][0]); us.y = f2bf(h_[a][1]); us.z = f2bf(h_[a][2]); us.w = f2bf(h_[a][3]);
    *(ushort4*)&Hg[base + row * 64 + j0] = us;
  }
  if (tid < 64) {
    float acc = 0.f;
    for (int n = 0; n < NN; ++n) acc += wya[n] * Lt[n * PIT + tid];
    bv[(size_t)t * 64 + tid] = acc;
  }
  red[tid] = cpart;
  __syncthreads();
  for (int o = 128; o; o >>= 1) {
    if (tid < o) red[tid] += red[tid + o];
    __syncthreads();
  }
  if (tid == 0) cv[t] = red[0];
  __syncthreads();
  red[tid] = apart;
  __syncthreads();
  for (int o = 128; o; o >>= 1) {
    if (tid < o) red[tid] += red[tid + o];
    __syncthreads();
  }
  if (tid == 0) aNv[t] = red[0];
}

// ---------------- MFMA fragment helpers (16x16x32 bf16) ----------------
// C = A * B^T, A,B row-major. A-frag: lane(ln,q) -> A[ti*16+ln][q*8+j];
// B-frag: B[tj*16+ln][q*8+j]; C-frag: col=tj*16+ln, row=ti*16+q*4+r.
__device__ __forceinline__ f32x4 mmLL(const u16* A, const u16* B, int ti, int tj,
                                      int ln, int q, f32x4 acc) {
  int ao = (ti * 16 + ln) * PB + q * 8;
  int bo = (tj * 16 + ln) * PB + q * 8;
#pragma unroll
  for (int k0 = 0; k0 < 64; k0 += 32)
    acc = __builtin_amdgcn_mfma_f32_16x16x32_bf16(*(const short8*)(A + ao + k0),
                                                  *(const short8*)(B + bo + k0), acc, 0, 0, 0);
  return acc;
}
__device__ __forceinline__ f32x4 mmLG(const u16* A, const u16* __restrict__ Bg, int ti,
                                      int tj, int ln, int q, f32x4 acc) {
  int ao = (ti * 16 + ln) * PB + q * 8;
  const u16* bp = Bg + (tj * 16 + ln) * 64 + q * 8;
#pragma unroll
  for (int k0 = 0; k0 < 64; k0 += 32)
    acc = __builtin_amdgcn_mfma_f32_16x16x32_bf16(*(const short8*)(A + ao + k0),
                                                  *(const short8*)(bp + k0), acc, 0, 0, 0);
  return acc;
}
__device__ __forceinline__ f32x4 mmGL(const u16* __restrict__ Ag, const u16* B, int ti,
                                      int tj, int ln, int q, f32x4 acc) {
  const u16* ap = Ag + (ti * 16 + ln) * 64 + q * 8;
  int bo = (tj * 16 + ln) * PB + q * 8;
#pragma unroll
  for (int k0 = 0; k0 < 64; k0 += 32)
    acc = __builtin_amdgcn_mfma_f32_16x16x32_bf16(*(const short8*)(ap + k0),
                                                  *(const short8*)(B + bo + k0), acc, 0, 0, 0);
  return acc;
}
__device__ __forceinline__ void stLDS(u16* Buf, int ti, int tj, int ln, int q, f32x4 v) {
  int col = tj * 16 + ln, rb = ti * 16 + q * 4;
#pragma unroll
  for (int r = 0; r < 4; ++r) Buf[(rb + r) * PB + col] = f2bf(v[r]);
}

// ---------------- K2: one Jacobi sweep (MFMA matmuls + scalar GJ) ------
__global__ __launch_bounds__(512) void k2(const u16* __restrict__ Sg, const u16* __restrict__ Gg,
                                          const u16* __restrict__ Hg, const u16* __restrict__ Pin,
                                          u16* __restrict__ Pout, u16* __restrict__ Wout,
                                          float* __restrict__ ldv, const float* __restrict__ hdr,
                                          const float* __restrict__ Qd,
                                          const u16* __restrict__ Ab16, int sweep, int last) {
  int t = blockIdx.x, tid = threadIdx.x;
  int lane = tid & 63, w = tid >> 6;
  int ln = lane & 15, q = lane >> 4;
  int ig = tid >> 4, jg = tid & 15, i0 = 2 * ig, j0 = 4 * jg;

  __shared__ __align__(16) u16 Pp16[64 * PB];   // P_pred bf16
  __shared__ __align__(16) float Ubuf[4608];    // M32 (fp32) OR Eb|Zb overlay
  __shared__ __align__(16) u16 XYb[64 * PB];    // X (then Y) bf16
  __shared__ __align__(16) u16 Wb[64 * PB];     // W bf16
  float* M32 = Ubuf;
  u16* Eb = (u16*)Ubuf;
  u16* Zb = (u16*)Ubuf + 64 * PB;

  float aS = hdr[0];
  bool diag = (hdr[1] != 0.f);

  // ---- Phase A: P_pred -> Pp16 (bf16) ----
  int row = tid >> 3, cg = tid & 7;
  float pv[8];
  if (t == 0) {
#pragma unroll
    for (int u = 0; u < 8; ++u) pv[u] = (cg * 8 + u == row) ? 1.f : 0.f;
  } else if (sweep == 0) {
#pragma unroll
    for (int u = 0; u < 8; ++u) pv[u] = (cg * 8 + u == row) ? 0.15f : 0.f;
  } else {
    uint4 raw = *(const uint4*)(Pin + (size_t)(t - 1) * 4096 + tid * 8);
    pv[0] = bf2f((u16)(raw.x & 0xffff)); pv[1] = bf2f((u16)(raw.x >> 16));
    pv[2] = bf2f((u16)(raw.y & 0xffff)); pv[3] = bf2f((u16)(raw.y >> 16));
    pv[4] = bf2f((u16)(raw.z & 0xffff)); pv[5] = bf2f((u16)(raw.z >> 16));
    pv[6] = bf2f((u16)(raw.w & 0xffff)); pv[7] = bf2f((u16)(raw.w >> 16));
  }
  if (diag) {
    float a2 = aS * aS;
    float qr = Qd[row];
    uint4 o;
    float v0 = a2 * pv[0] + ((cg * 8 + 0 == row) ? qr : 0.f);
    float v1 = a2 * pv[1] + ((cg * 8 + 1 == row) ? qr : 0.f);
    float v2 = a2 * pv[2] + ((cg * 8 + 2 == row) ? qr : 0.f);
    float v3 = a2 * pv[3] + ((cg * 8 + 3 == row) ? qr : 0.f);
    float v4 = a2 * pv[4] + ((cg * 8 + 4 == row) ? qr : 0.f);
    float v5 = a2 * pv[5] + ((cg * 8 + 5 == row) ? qr : 0.f);
    float v6 = a2 * pv[6] + ((cg * 8 + 6 == row) ? qr : 0.f);
    float v7 = a2 * pv[7] + ((cg * 8 + 7 == row) ? qr : 0.f);
    o.x = pack2(v0, v1); o.y = pack2(v2, v3); o.z = pack2(v4, v5); o.w = pack2(v6, v7);
    *(uint4*)&Pp16[row * PB + cg * 8] = o;
  } else {
    uint4 o;
    o.x = pack2(pv[0], pv[1]); o.y = pack2(pv[2], pv[3]);
    o.z = pack2(pv[4], pv[5]); o.w = pack2(pv[6], pv[7]);
    *(uint4*)&Pp16[row * PB + cg * 8] = o;
    __syncthreads();
#pragma unroll
    for (int tl = 0; tl < 2; ++tl) {
      int td = w + tl * 8, ti = td >> 2, tj = td & 3;
      f32x4 acc = {0.f, 0.f, 0.f, 0.f};
      acc = mmGL(Ab16, Pp16, ti, tj, ln, q, acc);
      stLDS(XYb, ti, tj, ln, q, acc);
    }
    __syncthreads();
#pragma unroll
    for (int tl = 0; tl < 2; ++tl) {
      int td = w + tl * 8, ti = td >> 2, tj = td & 3;
      f32x4 acc = {0.f, 0.f, 0.f, 0.f};
      acc = mmLG(XYb, Ab16, ti, tj, ln, q, acc);
      int col = tj * 16 + ln, rb = ti * 16 + q * 4;
#pragma unroll
      for (int r = 0; r < 4; ++r) {
        float v = acc[r] + ((rb + r) == col ? Qd[rb + r] : 0.f);
        Pp16[(rb + r) * PB + col] = f2bf(v);
      }
    }
  }
  __syncthreads();

  // ---- Phase B: M = I + P_pred * S  (fp32 into M32) ----
#pragma unroll
  for (int tl = 0; tl < 2; ++tl) {
    int td = w + tl * 8, ti = td >> 2, tj = td & 3;
    f32x4 acc = {0.f, 0.f, 0.f, 0.f};
    acc = mmLG(Pp16, Sg + (size_t)t * 4096, ti, tj, ln, q, acc);
    int col = tj * 16 + ln, rb = ti * 16 + q * 4;
#pragma unroll
    for (int r = 0; r < 4; ++r) M32[(rb + r) * PIT + col] = acc[r] + ((rb + r) == col ? 1.f : 0.f);
  }
  __syncthreads();

  // ---- Phase C: scalar Gauss-Jordan inverse (R1-proven), logdet on tid 0 ----
  float ldacc = 0.f;
  for (int j = 0; j < 64; ++j) {
    float piv = M32[j * PIT + j];
    float f0 = M32[i0 * PIT + j];
    float f1 = M32[(i0 + 1) * PIT + j];
    float4 pr4 = ldF4(&M32[j * PIT + j0]);
    __syncthreads();
    float ap = fabsf(piv);
    float pvv = (ap < 1e-12f) ? ((piv < 0.f) ? -1e-12f : 1e-12f) : piv;
    float pr = 1.0f / pvv;
    if (tid == 0) ldacc += logf(fabsf(pvv));
    float pj[4] = {pr4.x, pr4.y, pr4.z, pr4.w};
#pragma unroll
    for (int rr = 0; rr < 2; ++rr) {
      int i = i0 + rr;
      float f = rr ? f1 : f0;
      float4 cur = ldF4(&M32[i * PIT + j0]);
      float cu[4] = {cur.x, cur.y, cur.z, cur.w};
      float o[4];
#pragma unroll
      for (int c = 0; c < 4; ++c) {
        int k = j0 + c;
        float v;
        if (i == j)
          v = (k == j) ? pr : pj[c] * pr;
        else if (k == j)
          v = -f * pr;
        else
          v = cu[c] - f * pr * pj[c];
        o[c] = v;
      }
      *(float4*)&M32[i * PIT + j0] = make_float4(o[0], o[1], o[2], o[3]);
    }
    __syncthreads();
  }

  // ---- Phase D: Xb = bf16(M32) -> XYb ----
  {
    float4 x0 = ldF4(&M32[row * PIT + cg * 8]);
    float4 x1 = ldF4(&M32[row * PIT + cg * 8 + 4]);
    __syncthreads();
    uint4 o;
    o.x = pack2(x0.x, x0.y); o.y = pack2(x0.z, x0.w);
    o.z = pack2(x1.x, x1.y); o.w = pack2(x1.z, x1.w);
    *(uint4*)&XYb[row * PB + cg * 8] = o;
  }
  __syncthreads();

  // ---- Phase E: W = X * P_pred^T ----
#pragma unroll
  for (int tl = 0; tl < 2; ++tl) {
    int td = w + tl * 8, ti = td >> 2, tj = td & 3;
    f32x4 acc = {0.f, 0.f, 0.f, 0.f};
    acc = mmLL(XYb, Pp16, ti, tj, ln, q, acc);
    stLDS(Wb, ti, tj, ln, q, acc);
    if (last) {
      int col = tj * 16 + ln, rb = ti * 16 + q * 4;
#pragma unroll
      for (int r = 0; r < 4; ++r)
        Wout[(size_t)t * 4096 + (rb + r) * 64 + col] = f2bf(fin(acc[r]));
    }
  }
  __syncthreads();

  // ---- Phase F: E = I - W*G^T -> Eb ; Z = W*H^T -> Zb (overlay M32) ----
#pragma unroll
  for (int tl = 0; tl < 2; ++tl) {
    int td = w + tl * 8, ti = td >> 2, tj = td & 3;
    f32x4 e = {0.f, 0.f, 0.f, 0.f}, z = {0.f, 0.f, 0.f, 0.f};
    e = mmLG(Wb, Gg + (size_t)t * 4096, ti, tj, ln, q, e);
    z = mmLG(Wb, Hg + (size_t)t * 4096, ti, tj, ln, q, z);
    int col = tj * 16 + ln, rb = ti * 16 + q * 4;
#pragma unroll
    for (int r = 0; r < 4; ++r) {
      Eb[(rb + r) * PB + col] = f2bf(((rb + r) == col ? 1.f : 0.f) - e[r]);
      Zb[(rb + r) * PB + col] = f2bf(z[r]);
    }
  }
  __syncthreads();

  // ---- Phase G: C2 = Z*W^T (regs); Y = E*P_pred^T -> XYb ----
  f32x4 c2[2];
#pragma unroll
  for (int tl = 0; tl < 2; ++tl) {
    int td = w + tl * 8, ti = td >> 2, tj = td & 3;
    f32x4 acc = {0.f, 0.f, 0.f, 0.f};
    c2[tl] = mmLL(Zb, Wb, ti, tj, ln, q, acc);
    f32x4 y = {0.f, 0.f, 0.f, 0.f};
    y = mmLL(Eb, Pp16, ti, tj, ln, q, y);
    stLDS(XYb, ti, tj, ln, q, y);
  }
  __syncthreads();

  // ---- Phase H: P_upd = Y*E^T + C2 -> global (bf16, scrubbed) ----
#pragma unroll
  for (int tl = 0; tl < 2; ++tl) {
    int td = w + tl * 8, ti = td >> 2, tj = td & 3;
    f32x4 acc = c2[tl];
    acc = mmLL(XYb, Eb, ti, tj, ln, q, acc);
    int col = tj * 16 + ln, rb = ti * 16 + q * 4;
#pragma unroll
    for (int r = 0; r < 4; ++r)
      Pout[(size_t)t * 4096 + (rb + r) * 64 + col] = f2bf(fin(acc[r]));
  }
  if (last && tid == 0) ldv[t] = fin(ldacc);
}

// ---------------- K3: state + loglik, chunked parallel with warmup ----------------
#define OWN 16
#define WARM 48
__global__ __launch_bounds__(256) void k3(const u16* __restrict__ Gg, const u16* __restrict__ Wg,
                                          const float* __restrict__ bv, const float* __restrict__ cv,
                                          const float* __restrict__ aNv, const float* __restrict__ ldv,
                                          const float* __restrict__ hdr, const float* __restrict__ Asc,
                                          float* __restrict__ out) {
  int b = blockIdx.x, tid = threadIdx.x;
  int t0 = b * OWN;
  int tw = t0 - WARM;
  if (tw < 0) tw = 0;
  __shared__ __align__(16) float z[64], zp[64], q[64], wv[64], uu[64], part[256];
  float aS = hdr[0];
  bool diag = (hdr[1] != 0.f);
  float slr = hdr[2];
  if (tid < 64) z[tid] = 0.f;
  __syncthreads();
  for (int t = tw; t < t0 + OWN; ++t) {
    bool own = (t >= t0);
    if (tid < 64) {
      if (diag)
        zp[tid] = aS * z[tid];
      else {
        float s = 0.f;
        for (int k = 0; k < 64; k += 4) {
          float4 a = ldF4(&Asc[tid * 64 + k]);
          s += a.x * z[k] + a.y * z[k + 1] + a.z * z[k + 2] + a.w * z[k + 3];
        }
        zp[tid] = s;
      }
    }
    __syncthreads();
    {
      int i = tid & 63, seg = tid >> 6;
      const u16* Gr = Gg + (size_t)t * 4096 + i * 64 + seg * 16;
      float s = 0.f;
      for (int u = 0; u < 16; u += 4) {
        ushort4 g4 = *(const ushort4*)(Gr + u);
        const float* zz = &zp[seg * 16 + u];
        s += bf2f(g4.x) * zz[0] + bf2f(g4.y) * zz[1] + bf2f(g4.z) * zz[2] + bf2f(g4.w) * zz[3];
      }
      part[tid] = s;
    }
    __syncthreads();
    if (tid < 64) {
      float qi = part[tid] + part[tid + 64] + part[tid + 128] + part[tid + 192];
      q[tid] = qi;
      wv[tid] = bv[(size_t)t * 64 + tid] - qi;
    }
    __syncthreads();
    {
      int i = tid & 63, seg = tid >> 6;
      const u16* Wr = Wg + (size_t)t * 4096 + i * 64 + seg * 16;
      float s = 0.f;
      for (int u = 0; u < 16; u += 4) {
        ushort4 g4 = *(const ushort4*)(Wr + u);
        const float* zz = &wv[seg * 16 + u];
        s += bf2f(g4.x) * zz[0] + bf2f(g4.y) * zz[1] + bf2f(g4.z) * zz[2] + bf2f(g4.w) * zz[3];
      }
      part[tid] = s;
    }
    __syncthreads();
    if (tid < 64) {
      float ui = part[tid] + part[tid + 64] + part[tid + 128] + part[tid + 192];
      uu[tid] = ui;
      float zi = zp[tid] + ui;
      z[tid] = isfinite(zi) ? zi : 0.f;
    }
    __syncthreads();
    if (tid < 64) {
      float bz = bv[(size_t)t * 64 + tid] * zp[tid];
      float zq = zp[tid] * q[tid];
      float wu = wv[tid] * uu[tid];
      for (int o = 32; o; o >>= 1) {
        bz += __shfl_down(bz, o);
        zq += __shfl_down(zq, o);
        wu += __shfl_down(wu, o);
      }
      if (tid == 0 && own) {
        float mahal = cv[t] - 2.f * bz + zq - wu;
        float ll = -0.5f * (aNv[t] * LOG2PI + slr + ldv[t] + mahal);
        if (!isfinite(ll)) ll = -1e6f;
        out[(size_t)t * 65 + 64] = ll;
      }
      if (own) out[(size_t)t * 65 + tid] = z[tid];
    }
    __syncthreads();
  }
}

extern "C" void kernel_launch(void* const* d_in, const int* in_sizes, int n_in,
                              void* d_out, int out_size, void* d_ws, size_t ws_size,
                              hipStream_t stream) {
  const float* obs = (const float*)d_in[0];
  const float* Lam = (const float*)d_in[1];
  const float* Araw = (const float*)d_in[2];
  const float* logQ = (const float*)d_in[3];
  const float* logR = (const float*)d_in[4];
  float* out = (float*)d_out;

  char* w = (char*)d_ws;
  float* hdr = (float*)w;
  float* Qd = hdr + 64;
  float* Asc = hdr + 128;
  u16* Ab16 = (u16*)(hdr + 4224);
  const size_t MB = (size_t)TT * 4096;
  u16* Sg = (u16*)(w + 32768);
  u16* Gg = Sg + MB;
  u16* Hg = Gg + MB;
  u16* Wg = Hg + MB;
  u16* Pb0 = Wg + MB;
  u16* Pb1 = Pb0 + MB;
  float* bv = (float*)(Pb1 + MB);
  float* cv = bv + (size_t)TT * 64;
  float* aNv = cv + TT;
  float* ldv = aNv + TT;

  k0<<<dim3(1), dim3(256), 0, stream>>>(Araw, logQ, logR, hdr, Qd, Asc, Ab16);
  k1<<<dim3(TT), dim3(256), 0, stream>>>(obs, Lam, logR, Sg, Gg, Hg, bv, cv, aNv);
  for (int s = 0; s < NSWEEPS; ++s) {
    const u16* pin = (s & 1) ? Pb1 : Pb0;
    u16* pout = (s & 1) ? Pb0 : Pb1;
    k2<<<dim3(TT), dim3(512), 0, stream>>>(Sg, Gg, Hg, pin, pout, Wg, ldv, hdr, Qd, Ab16, s,
                                           (s == NSWEEPS - 1) ? 1 : 0);
  }
  k3<<<dim3(TT / OWN), dim3(256), 0, stream>>>(Gg, Wg, bv, cv, aNv, ldv, hdr, Asc, out);
}

// Round 4
// 1246.669 us; speedup vs baseline: 3.6209x; 1.5711x over previous
//
#include <hip/hip_runtime.h>

// LTV Kalman filter, GPU-restructured (Woodbury + parallel Jacobi-Riccati).
// R4: k1 moved to MFMA (bf16 L^T staged in LDS, 3 weighted passes),
// NSWEEPS 8->5 (contraction ~0.03/sweep; error floor is output bf16),
// k3 chunk OWN=4/WARM=16 (state forgets at ~0.16/step).

#define TT 2048
#define NN 256
#define KKD 64
#define PIT 68      // fp32 LDS pitch
#define PB 72       // bf16 LDS pitch (k2 64x64 tiles)
#define PL 264      // bf16 LDS pitch for k1 64x256 L^T tiles
#define NSWEEPS 5
#define LOG2PI 1.8378770664093453f

typedef unsigned short u16;
typedef unsigned int u32;
typedef __attribute__((ext_vector_type(8))) short short8;
typedef __attribute__((ext_vector_type(4))) float f32x4;

__device__ __forceinline__ float bf2f(u16 u) {
  u32 x = ((u32)u) << 16;
  return __uint_as_float(x);
}
__device__ __forceinline__ u16 f2bf(float f) {
  u32 u = __float_as_uint(f);
  u32 r = (u + 0x7fffu + ((u >> 16) & 1u)) >> 16;
  return (u16)r;
}
__device__ __forceinline__ u32 pack2(float a, float b) {
  return (u32)f2bf(a) | ((u32)f2bf(b) << 16);
}
__device__ __forceinline__ float4 ldF4(const float* p) { return *(const float4*)p; }
__device__ __forceinline__ float fin(float v) { return isfinite(v) ? v : 0.f; }

// ---------------- K0: scalars ----------------
__global__ __launch_bounds__(256) void k0(const float* __restrict__ Araw,
                                          const float* __restrict__ logQ,
                                          const float* __restrict__ logR,
                                          float* hdr, float* Qd, float* Asc, u16* Ab16) {
  __shared__ __align__(16) float Bm[64 * PIT];
  __shared__ __align__(16) float red[256];
  __shared__ __align__(16) float vv[64];
  int tid = threadIdx.x;
  if (tid < 64) Qd[tid] = expf(logQ[tid]);
  float r = expf(logR[tid]);
  red[tid] = logf(r + 1e-4f);
  __syncthreads();
  for (int o = 128; o; o >>= 1) {
    if (tid < o) red[tid] += red[tid + o];
    __syncthreads();
  }
  if (tid == 0) hdr[2] = red[0];
  __syncthreads();
  float a0 = Araw[0];
  float okf = 1.0f;
  for (int u = 0; u < 16; ++u) {
    int idx = tid * 16 + u;
    int i = idx >> 6, j = idx & 63;
    float v = Araw[idx];
    bool good = (i == j) ? (v == a0) : (v == 0.0f);
    if (!good) okf = 0.0f;
  }
  red[tid] = okf;
  __syncthreads();
  for (int o = 128; o; o >>= 1) {
    if (tid < o) red[tid] = fminf(red[tid], red[tid + o]);
    __syncthreads();
  }
  float isDiag = red[0];
  __syncthreads();
  for (int u = 0; u < 16; ++u) {
    int idx = tid * 16 + u;
    int i = idx >> 6, j = idx & 63;
    float s = 0.f;
    for (int k = 0; k < 64; ++k) s += Araw[k * 64 + i] * Araw[k * 64 + j];
    Bm[i * PIT + j] = s;
  }
  __syncthreads();
  if (tid < 64) {
    vv[tid] = 1.0f;
    float lam = 0.f;
    for (int it = 0; it < 64; ++it) {
      float ui = 0.f;
      for (int k = 0; k < 64; ++k) ui += Bm[tid * PIT + k] * vv[k];
      float s = ui * ui;
      for (int o = 32; o; o >>= 1) s += __shfl_down(s, o);
      float n2 = __shfl(s, 0);
      float nr = sqrtf(fmaxf(n2, 1e-30f));
      vv[tid] = ui / nr;
      lam = nr;
    }
    if (tid == 0) red[0] = lam;
  }
  __syncthreads();
  float sig = sqrtf(fmaxf(red[0], 0.f));
  float scale = 0.98f / (sig + 1e-6f);
  if (tid == 0) {
    hdr[0] = scale * a0;
    hdr[1] = isDiag;
    hdr[3] = sig;
  }
  for (int u = 0; u < 16; ++u) {
    int idx = tid * 16 + u;
    float v = scale * Araw[idx];
    Asc[idx] = v;
    Ab16[idx] = f2bf(v);
  }
}

// ---------------- K1: per-t Woodbury precompute via MFMA ----------------
// S = L^T diag(w1) L, G = .. w2 .., H = .. w3 ..  ; contraction dim n=256.
// Lt LDS holds L^T (64 rows x 256 cols bf16); LtW = row-wise w-weighted copy.
__global__ __launch_bounds__(512) void k1(const float* __restrict__ obs,
                                          const float* __restrict__ Lam,
                                          const float* __restrict__ logR,
                                          u16* __restrict__ Sg, u16* __restrict__ Gg,
                                          u16* __restrict__ Hg, float* __restrict__ bv,
                                          float* __restrict__ cv, float* __restrict__ aNv) {
  int t = blockIdx.x, tid = threadIdx.x;
  __shared__ __align__(16) u16 Lt[64 * PL];
  __shared__ __align__(16) u16 LtW[64 * PL];
  __shared__ __align__(16) float w1a[NN], w2a[NN], w3a[NN], wya[NN];
  __shared__ __align__(16) float red[512];
  int lane = tid & 63, wv = tid >> 6;
  int ln = lane & 15, q = lane >> 4;

  float cpart = 0.f, apart = 0.f;
  if (tid < NN) {
    float y = obs[(size_t)t * NN + tid];
    float r = expf(logR[tid]);
    float re = r + 1e-4f;
    float w1 = 1.0f / re;
    bool m = (y != y);
    w1a[tid] = w1;
    w2a[tid] = m ? 0.f : w1;
    w3a[tid] = m ? 0.f : r / (re * re);
    wya[tid] = m ? 0.f : (w1 * y);
    cpart = m ? 0.f : (w1 * y * y);
    apart = m ? 0.f : 1.f;
  }
  // stage L^T (transpose, fp32 -> bf16)
  const float4* Lsrc = (const float4*)(Lam + (size_t)t * NN * KKD);
  for (int u = 0; u < 8; ++u) {
    int fl = u * 512 + tid;  // 4096 float4s
    float4 v = Lsrc[fl];
    int n = fl >> 4, k0 = (fl & 15) * 4;
    Lt[(k0 + 0) * PL + n] = f2bf(v.x);
    Lt[(k0 + 1) * PL + n] = f2bf(v.y);
    Lt[(k0 + 2) * PL + n] = f2bf(v.z);
    Lt[(k0 + 3) * PL + n] = f2bf(v.w);
  }
  __syncthreads();

  const float* Ws[3] = {w1a, w2a, w3a};
  u16* Os[3] = {Sg + (size_t)t * 4096, Gg + (size_t)t * 4096, Hg + (size_t)t * 4096};
#pragma unroll
  for (int m = 0; m < 3; ++m) {
    const float* W = Ws[m];
    // LtW = w ⊙ Lt  (row-wise scale, contiguous)
    for (int u = 0; u < 4; ++u) {
      int fl = u * 512 + tid;          // 2048 chunks of 8
      int row = fl >> 5, c8 = (fl & 31) * 8;
      ushort4 lo = *(const ushort4*)&Lt[row * PL + c8];
      ushort4 hi = *(const ushort4*)&Lt[row * PL + c8 + 4];
      float4 wa = ldF4(&W[c8]);
      float4 wb = ldF4(&W[c8 + 4]);
      ushort4 olo, ohi;
      olo.x = f2bf(bf2f(lo.x) * wa.x); olo.y = f2bf(bf2f(lo.y) * wa.y);
      olo.z = f2bf(bf2f(lo.z) * wa.z); olo.w = f2bf(bf2f(lo.w) * wa.w);
      ohi.x = f2bf(bf2f(hi.x) * wb.x); ohi.y = f2bf(bf2f(hi.y) * wb.y);
      ohi.z = f2bf(bf2f(hi.z) * wb.z); ohi.w = f2bf(bf2f(hi.w) * wb.w);
      *(ushort4*)&LtW[row * PL + c8] = olo;
      *(ushort4*)&LtW[row * PL + c8 + 4] = ohi;
    }
    __syncthreads();
    // C = Lt * LtW^T : 16 tiles (4x4), 2 per wave
    u16* O = Os[m];
#pragma unroll
    for (int tl = 0; tl < 2; ++tl) {
      int td = wv + tl * 8, ti = td >> 2, tj = td & 3;
      f32x4 acc = {0.f, 0.f, 0.f, 0.f};
#pragma unroll
      for (int n0 = 0; n0 < 256; n0 += 32)
        acc = __builtin_amdgcn_mfma_f32_16x16x32_bf16(
            *(const short8*)&Lt[(ti * 16 + ln) * PL + n0 + q * 8],
            *(const short8*)&LtW[(tj * 16 + ln) * PL + n0 + q * 8], acc, 0, 0, 0);
      int col = tj * 16 + ln, rb = ti * 16 + q * 4;
#pragma unroll
      for (int r = 0; r < 4; ++r) O[(rb + r) * 64 + col] = f2bf(acc[r]);
    }
    __syncthreads();
  }

  // b[k] = sum_n wya[n] * Lt[k][n]
  {
    int k = tid >> 3, seg = tid & 7;
    float s = 0.f;
    for (int n = seg * 32; n < seg * 32 + 32; n += 4) {
      ushort4 l4 = *(const ushort4*)&Lt[k * PL + n];
      float4 wy = ldF4(&wya[n]);
      s += bf2f(l4.x) * wy.x + bf2f(l4.y) * wy.y + bf2f(l4.z) * wy.z + bf2f(l4.w) * wy.w;
    }
    red[tid] = s;
  }
  __syncthreads();
  if (tid < 64) {
    float acc = 0.f;
#pragma unroll
    for (int s = 0; s < 8; ++s) acc += red[tid * 8 + s];
    bv[(size_t)t * 64 + tid] = acc;
  }
  __syncthreads();
  red[tid] = cpart;
  __syncthreads();
  for (int o = 256; o; o >>= 1) {
    if (tid < o) red[tid] += red[tid + o];
    __syncthreads();
  }
  if (tid == 0) cv[t] = red[0];
  __syncthreads();
  red[tid] = apart;
  __syncthreads();
  for (int o = 256; o; o >>= 1) {
    if (tid < o) red[tid] += red[tid + o];
    __syncthreads();
  }
  if (tid == 0) aNv[t] = red[0];
}

// ---------------- MFMA fragment helpers (16x16x32 bf16) ----------------
__device__ __forceinline__ f32x4 mmLL(const u16* A, const u16* B, int ti, int tj,
                                      int ln, int q, f32x4 acc) {
  int ao = (ti * 16 + ln) * PB + q * 8;
  int bo = (tj * 16 + ln) * PB + q * 8;
#pragma unroll
  for (int k0 = 0; k0 < 64; k0 += 32)
    acc = __builtin_amdgcn_mfma_f32_16x16x32_bf16(*(const short8*)(A + ao + k0),
                                                  *(const short8*)(B + bo + k0), acc, 0, 0, 0);
  return acc;
}
__device__ __forceinline__ f32x4 mmLG(const u16* A, const u16* __restrict__ Bg, int ti,
                                      int tj, int ln, int q, f32x4 acc) {
  int ao = (ti * 16 + ln) * PB + q * 8;
  const u16* bp = Bg + (tj * 16 + ln) * 64 + q * 8;
#pragma unroll
  for (int k0 = 0; k0 < 64; k0 += 32)
    acc = __builtin_amdgcn_mfma_f32_16x16x32_bf16(*(const short8*)(A + ao + k0),
                                                  *(const short8*)(bp + k0), acc, 0, 0, 0);
  return acc;
}
__device__ __forceinline__ f32x4 mmGL(const u16* __restrict__ Ag, const u16* B, int ti,
                                      int tj, int ln, int q, f32x4 acc) {
  const u16* ap = Ag + (ti * 16 + ln) * 64 + q * 8;
  int bo = (tj * 16 + ln) * PB + q * 8;
#pragma unroll
  for (int k0 = 0; k0 < 64; k0 += 32)
    acc = __builtin_amdgcn_mfma_f32_16x16x32_bf16(*(const short8*)(ap + k0),
                                                  *(const short8*)(B + bo + k0), acc, 0, 0, 0);
  return acc;
}
__device__ __forceinline__ void stLDS(u16* Buf, int ti, int tj, int ln, int q, f32x4 v) {
  int col = tj * 16 + ln, rb = ti * 16 + q * 4;
#pragma unroll
  for (int r = 0; r < 4; ++r) Buf[(rb + r) * PB + col] = f2bf(v[r]);
}

// ---------------- K2: one Jacobi sweep (MFMA matmuls + scalar GJ) ------
__global__ __launch_bounds__(512) void k2(const u16* __restrict__ Sg, const u16* __restrict__ Gg,
                                          const u16* __restrict__ Hg, const u16* __restrict__ Pin,
                                          u16* __restrict__ Pout, u16* __restrict__ Wout,
                                          float* __restrict__ ldv, const float* __restrict__ hdr,
                                          const float* __restrict__ Qd,
                                          const u16* __restrict__ Ab16, int sweep, int last) {
  int t = blockIdx.x, tid = threadIdx.x;
  int lane = tid & 63, w = tid >> 6;
  int ln = lane & 15, q = lane >> 4;
  int ig = tid >> 4, i0 = 2 * ig, j0 = 4 * (tid & 15);

  __shared__ __align__(16) u16 Pp16[64 * PB];
  __shared__ __align__(16) float Ubuf[4608];
  __shared__ __align__(16) u16 XYb[64 * PB];
  __shared__ __align__(16) u16 Wb[64 * PB];
  float* M32 = Ubuf;
  u16* Eb = (u16*)Ubuf;
  u16* Zb = (u16*)Ubuf + 64 * PB;

  float aS = hdr[0];
  bool diag = (hdr[1] != 0.f);

  // ---- Phase A: P_pred -> Pp16 (bf16) ----
  int row = tid >> 3, cg = tid & 7;
  float pv[8];
  if (t == 0) {
#pragma unroll
    for (int u = 0; u < 8; ++u) pv[u] = (cg * 8 + u == row) ? 1.f : 0.f;
  } else if (sweep == 0) {
#pragma unroll
    for (int u = 0; u < 8; ++u) pv[u] = (cg * 8 + u == row) ? 0.15f : 0.f;
  } else {
    uint4 raw = *(const uint4*)(Pin + (size_t)(t - 1) * 4096 + tid * 8);
    pv[0] = bf2f((u16)(raw.x & 0xffff)); pv[1] = bf2f((u16)(raw.x >> 16));
    pv[2] = bf2f((u16)(raw.y & 0xffff)); pv[3] = bf2f((u16)(raw.y >> 16));
    pv[4] = bf2f((u16)(raw.z & 0xffff)); pv[5] = bf2f((u16)(raw.z >> 16));
    pv[6] = bf2f((u16)(raw.w & 0xffff)); pv[7] = bf2f((u16)(raw.w >> 16));
  }
  if (diag) {
    float a2 = aS * aS;
    float qr = Qd[row];
    uint4 o;
    float v0 = a2 * pv[0] + ((cg * 8 + 0 == row) ? qr : 0.f);
    float v1 = a2 * pv[1] + ((cg * 8 + 1 == row) ? qr : 0.f);
    float v2 = a2 * pv[2] + ((cg * 8 + 2 == row) ? qr : 0.f);
    float v3 = a2 * pv[3] + ((cg * 8 + 3 == row) ? qr : 0.f);
    float v4 = a2 * pv[4] + ((cg * 8 + 4 == row) ? qr : 0.f);
    float v5 = a2 * pv[5] + ((cg * 8 + 5 == row) ? qr : 0.f);
    float v6 = a2 * pv[6] + ((cg * 8 + 6 == row) ? qr : 0.f);
    float v7 = a2 * pv[7] + ((cg * 8 + 7 == row) ? qr : 0.f);
    o.x = pack2(v0, v1); o.y = pack2(v2, v3); o.z = pack2(v4, v5); o.w = pack2(v6, v7);
    *(uint4*)&Pp16[row * PB + cg * 8] = o;
  } else {
    uint4 o;
    o.x = pack2(pv[0], pv[1]); o.y = pack2(pv[2], pv[3]);
    o.z = pack2(pv[4], pv[5]); o.w = pack2(pv[6], pv[7]);
    *(uint4*)&Pp16[row * PB + cg * 8] = o;
    __syncthreads();
#pragma unroll
    for (int tl = 0; tl < 2; ++tl) {
      int td = w + tl * 8, ti = td >> 2, tj = td & 3;
      f32x4 acc = {0.f, 0.f, 0.f, 0.f};
      acc = mmGL(Ab16, Pp16, ti, tj, ln, q, acc);
      stLDS(XYb, ti, tj, ln, q, acc);
    }
    __syncthreads();
#pragma unroll
    for (int tl = 0; tl < 2; ++tl) {
      int td = w + tl * 8, ti = td >> 2, tj = td & 3;
      f32x4 acc = {0.f, 0.f, 0.f, 0.f};
      acc = mmLG(XYb, Ab16, ti, tj, ln, q, acc);
      int col = tj * 16 + ln, rb = ti * 16 + q * 4;
#pragma unroll
      for (int r = 0; r < 4; ++r) {
        float v = acc[r] + ((rb + r) == col ? Qd[rb + r] : 0.f);
        Pp16[(rb + r) * PB + col] = f2bf(v);
      }
    }
  }
  __syncthreads();

  // ---- Phase B: M = I + P_pred * S ----
#pragma unroll
  for (int tl = 0; tl < 2; ++tl) {
    int td = w + tl * 8, ti = td >> 2, tj = td & 3;
    f32x4 acc = {0.f, 0.f, 0.f, 0.f};
    acc = mmLG(Pp16, Sg + (size_t)t * 4096, ti, tj, ln, q, acc);
    int col = tj * 16 + ln, rb = ti * 16 + q * 4;
#pragma unroll
    for (int r = 0; r < 4; ++r) M32[(rb + r) * PIT + col] = acc[r] + ((rb + r) == col ? 1.f : 0.f);
  }
  __syncthreads();

  // ---- Phase C: scalar Gauss-Jordan inverse, logdet on tid 0 ----
  float ldacc = 0.f;
  for (int j = 0; j < 64; ++j) {
    float piv = M32[j * PIT + j];
    float f0 = M32[i0 * PIT + j];
    float f1 = M32[(i0 + 1) * PIT + j];
    float4 pr4 = ldF4(&M32[j * PIT + j0]);
    __syncthreads();
    float ap = fabsf(piv);
    float pvv = (ap < 1e-12f) ? ((piv < 0.f) ? -1e-12f : 1e-12f) : piv;
    float pr = 1.0f / pvv;
    if (tid == 0) ldacc += logf(fabsf(pvv));
    float pj[4] = {pr4.x, pr4.y, pr4.z, pr4.w};
#pragma unroll
    for (int rr = 0; rr < 2; ++rr) {
      int i = i0 + rr;
      float f = rr ? f1 : f0;
      float4 cur = ldF4(&M32[i * PIT + j0]);
      float cu[4] = {cur.x, cur.y, cur.z, cur.w};
      float o[4];
#pragma unroll
      for (int c = 0; c < 4; ++c) {
        int k = j0 + c;
        float v;
        if (i == j)
          v = (k == j) ? pr : pj[c] * pr;
        else if (k == j)
          v = -f * pr;
        else
          v = cu[c] - f * pr * pj[c];
        o[c] = v;
      }
      *(float4*)&M32[i * PIT + j0] = make_float4(o[0], o[1], o[2], o[3]);
    }
    __syncthreads();
  }

  // ---- Phase D: Xb = bf16(M32) -> XYb ----
  {
    float4 x0 = ldF4(&M32[row * PIT + cg * 8]);
    float4 x1 = ldF4(&M32[row * PIT + cg * 8 + 4]);
    __syncthreads();
    uint4 o;
    o.x = pack2(x0.x, x0.y); o.y = pack2(x0.z, x0.w);
    o.z = pack2(x1.x, x1.y); o.w = pack2(x1.z, x1.w);
    *(uint4*)&XYb[row * PB + cg * 8] = o;
  }
  __syncthreads();

  // ---- Phase E: W = X * P_pred^T ----
#pragma unroll
  for (int tl = 0; tl < 2; ++tl) {
    int td = w + tl * 8, ti = td >> 2, tj = td & 3;
    f32x4 acc = {0.f, 0.f, 0.f, 0.f};
    acc = mmLL(XYb, Pp16, ti, tj, ln, q, acc);
    stLDS(Wb, ti, tj, ln, q, acc);
    if (last) {
      int col = tj * 16 + ln, rb = ti * 16 + q * 4;
#pragma unroll
      for (int r = 0; r < 4; ++r)
        Wout[(size_t)t * 4096 + (rb + r) * 64 + col] = f2bf(fin(acc[r]));
    }
  }
  __syncthreads();

  // ---- Phase F: E = I - W*G^T -> Eb ; Z = W*H^T -> Zb ----
#pragma unroll
  for (int tl = 0; tl < 2; ++tl) {
    int td = w + tl * 8, ti = td >> 2, tj = td & 3;
    f32x4 e = {0.f, 0.f, 0.f, 0.f}, z = {0.f, 0.f, 0.f, 0.f};
    e = mmLG(Wb, Gg + (size_t)t * 4096, ti, tj, ln, q, e);
    z = mmLG(Wb, Hg + (size_t)t * 4096, ti, tj, ln, q, z);
    int col = tj * 16 + ln, rb = ti * 16 + q * 4;
#pragma unroll
    for (int r = 0; r < 4; ++r) {
      Eb[(rb + r) * PB + col] = f2bf(((rb + r) == col ? 1.f : 0.f) - e[r]);
      Zb[(rb + r) * PB + col] = f2bf(z[r]);
    }
  }
  __syncthreads();

  // ---- Phase G: C2 = Z*W^T (regs); Y = E*P_pred^T -> XYb ----
  f32x4 c2[2];
#pragma unroll
  for (int tl = 0; tl < 2; ++tl) {
    int td = w + tl * 8, ti = td >> 2, tj = td & 3;
    f32x4 acc = {0.f, 0.f, 0.f, 0.f};
    c2[tl] = mmLL(Zb, Wb, ti, tj, ln, q, acc);
    f32x4 y = {0.f, 0.f, 0.f, 0.f};
    y = mmLL(Eb, Pp16, ti, tj, ln, q, y);
    stLDS(XYb, ti, tj, ln, q, y);
  }
  __syncthreads();

  // ---- Phase H: P_upd = Y*E^T + C2 -> global ----
#pragma unroll
  for (int tl = 0; tl < 2; ++tl) {
    int td = w + tl * 8, ti = td >> 2, tj = td & 3;
    f32x4 acc = c2[tl];
    acc = mmLL(XYb, Eb, ti, tj, ln, q, acc);
    int col = tj * 16 + ln, rb = ti * 16 + q * 4;
#pragma unroll
    for (int r = 0; r < 4; ++r)
      Pout[(size_t)t * 4096 + (rb + r) * 64 + col] = f2bf(fin(acc[r]));
  }
  if (last && tid == 0) ldv[t] = fin(ldacc);
}

// ---------------- K3: state + loglik, chunked parallel with warmup ----------------
#define OWN 4
#define WARM 16
__global__ __launch_bounds__(256) void k3(const u16* __restrict__ Gg, const u16* __restrict__ Wg,
                                          const float* __restrict__ bv, const float* __restrict__ cv,
                                          const float* __restrict__ aNv, const float* __restrict__ ldv,
                                          const float* __restrict__ hdr, const float* __restrict__ Asc,
                                          float* __restrict__ out) {
  int b = blockIdx.x, tid = threadIdx.x;
  int t0 = b * OWN;
  int tw = t0 - WARM;
  if (tw < 0) tw = 0;
  __shared__ __align__(16) float z[64], zp[64], q[64], wv[64], uu[64], part[256];
  float aS = hdr[0];
  bool diag = (hdr[1] != 0.f);
  float slr = hdr[2];
  if (tid < 64) z[tid] = 0.f;
  __syncthreads();
  for (int t = tw; t < t0 + OWN; ++t) {
    bool own = (t >= t0);
    if (tid < 64) {
      if (diag)
        zp[tid] = aS * z[tid];
      else {
        float s = 0.f;
        for (int k = 0; k < 64; k += 4) {
          float4 a = ldF4(&Asc[tid * 64 + k]);
          s += a.x * z[k] + a.y * z[k + 1] + a.z * z[k + 2] + a.w * z[k + 3];
        }
        zp[tid] = s;
      }
    }
    __syncthreads();
    {
      int i = tid & 63, seg = tid >> 6;
      const u16* Gr = Gg + (size_t)t * 4096 + i * 64 + seg * 16;
      float s = 0.f;
      for (int u = 0; u < 16; u += 4) {
        ushort4 g4 = *(const ushort4*)(Gr + u);
        const float* zz = &zp[seg * 16 + u];
        s += bf2f(g4.x) * zz[0] + bf2f(g4.y) * zz[1] + bf2f(g4.z) * zz[2] + bf2f(g4.w) * zz[3];
      }
      part[tid] = s;
    }
    __syncthreads();
    if (tid < 64) {
      float qi = part[tid] + part[tid + 64] + part[tid + 128] + part[tid + 192];
      q[tid] = qi;
      wv[tid] = bv[(size_t)t * 64 + tid] - qi;
    }
    __syncthreads();
    {
      int i = tid & 63, seg = tid >> 6;
      const u16* Wr = Wg + (size_t)t * 4096 + i * 64 + seg * 16;
      float s = 0.f;
      for (int u = 0; u < 16; u += 4) {
        ushort4 g4 = *(const ushort4*)(Wr + u);
        const float* zz = &wv[seg * 16 + u];
        s += bf2f(g4.x) * zz[0] + bf2f(g4.y) * zz[1] + bf2f(g4.z) * zz[2] + bf2f(g4.w) * zz[3];
      }
      part[tid] = s;
    }
    __syncthreads();
    if (tid < 64) {
      float ui = part[tid] + part[tid + 64] + part[tid + 128] + part[tid + 192];
      uu[tid] = ui;
      float zi = zp[tid] + ui;
      z[tid] = isfinite(zi) ? zi : 0.f;
    }
    __syncthreads();
    if (tid < 64) {
      float bz = bv[(size_t)t * 64 + tid] * zp[tid];
      float zq = zp[tid] * q[tid];
      float wu = wv[tid] * uu[tid];
      for (int o = 32; o; o >>= 1) {
        bz += __shfl_down(bz, o);
        zq += __shfl_down(zq, o);
        wu += __shfl_down(wu, o);
      }
      if (tid == 0 && own) {
        float mahal = cv[t] - 2.f * bz + zq - wu;
        float ll = -0.5f * (aNv[t] * LOG2PI + slr + ldv[t] + mahal);
        if (!isfinite(ll)) ll = -1e6f;
        out[(size_t)t * 65 + 64] = ll;
      }
      if (own) out[(size_t)t * 65 + tid] = z[tid];
    }
    __syncthreads();
  }
}

extern "C" void kernel_launch(void* const* d_in, const int* in_sizes, int n_in,
                              void* d_out, int out_size, void* d_ws, size_t ws_size,
                              hipStream_t stream) {
  const float* obs = (const float*)d_in[0];
  const float* Lam = (const float*)d_in[1];
  const float* Araw = (const float*)d_in[2];
  const float* logQ = (const float*)d_in[3];
  const float* logR = (const float*)d_in[4];
  float* out = (float*)d_out;

  char* w = (char*)d_ws;
  float* hdr = (float*)w;
  float* Qd = hdr + 64;
  float* Asc = hdr + 128;
  u16* Ab16 = (u16*)(hdr + 4224);
  const size_t MB = (size_t)TT * 4096;
  u16* Sg = (u16*)(w + 32768);
  u16* Gg = Sg + MB;
  u16* Hg = Gg + MB;
  u16* Wg = Hg + MB;
  u16* Pb0 = Wg + MB;
  u16* Pb1 = Pb0 + MB;
  float* bv = (float*)(Pb1 + MB);
  float* cv = bv + (size_t)TT * 64;
  float* aNv = cv + TT;
  float* ldv = aNv + TT;

  k0<<<dim3(1), dim3(256), 0, stream>>>(Araw, logQ, logR, hdr, Qd, Asc, Ab16);
  k1<<<dim3(TT), dim3(512), 0, stream>>>(obs, Lam, logR, Sg, Gg, Hg, bv, cv, aNv);
  for (int s = 0; s < NSWEEPS; ++s) {
    const u16* pin = (s & 1) ? Pb1 : Pb0;
    u16* pout = (s & 1) ? Pb0 : Pb1;
    k2<<<dim3(TT), dim3(512), 0, stream>>>(Sg, Gg, Hg, pin, pout, Wg, ldv, hdr, Qd, Ab16, s,
                                           (s == NSWEEPS - 1) ? 1 : 0);
  }
  k3<<<dim3(TT / OWN), dim3(256), 0, stream>>>(Gg, Wg, bv, cv, aNv, ldv, hdr, Asc, out);
}

// Round 5
// 800.762 us; speedup vs baseline: 5.6371x; 1.5569x over previous
//
#include <hip/hip_runtime.h>

// LTV Kalman filter, GPU-restructured (Woodbury + parallel Jacobi-Riccati).
// R5: register-resident Gauss-Jordan (pivot multipliers via __shfl, one
// ds_read_b128 + 16-thread ds_write_b128 + ONE barrier per iter), direct
// reg->bf16 pack of the inverse; NSWEEPS 5->4.

#define TT 2048
#define NN 256
#define KKD 64
#define PIT 68      // fp32 LDS pitch
#define PB 72       // bf16 LDS pitch (k2 64x64 tiles)
#define PL 264      // bf16 LDS pitch for k1 64x256 L^T tiles
#define NSWEEPS 4
#define LOG2PI 1.8378770664093453f

typedef unsigned short u16;
typedef unsigned int u32;
typedef __attribute__((ext_vector_type(8))) short short8;
typedef __attribute__((ext_vector_type(4))) float f32x4;

__device__ __forceinline__ float bf2f(u16 u) {
  u32 x = ((u32)u) << 16;
  return __uint_as_float(x);
}
__device__ __forceinline__ u16 f2bf(float f) {
  u32 u = __float_as_uint(f);
  u32 r = (u + 0x7fffu + ((u >> 16) & 1u)) >> 16;
  return (u16)r;
}
__device__ __forceinline__ u32 pack2(float a, float b) {
  return (u32)f2bf(a) | ((u32)f2bf(b) << 16);
}
__device__ __forceinline__ float4 ldF4(const float* p) { return *(const float4*)p; }
__device__ __forceinline__ float fin(float v) { return isfinite(v) ? v : 0.f; }

// ---------------- K0: scalars ----------------
__global__ __launch_bounds__(256) void k0(const float* __restrict__ Araw,
                                          const float* __restrict__ logQ,
                                          const float* __restrict__ logR,
                                          float* hdr, float* Qd, float* Asc, u16* Ab16) {
  __shared__ __align__(16) float Bm[64 * PIT];
  __shared__ __align__(16) float red[256];
  __shared__ __align__(16) float vv[64];
  int tid = threadIdx.x;
  if (tid < 64) Qd[tid] = expf(logQ[tid]);
  float r = expf(logR[tid]);
  red[tid] = logf(r + 1e-4f);
  __syncthreads();
  for (int o = 128; o; o >>= 1) {
    if (tid < o) red[tid] += red[tid + o];
    __syncthreads();
  }
  if (tid == 0) hdr[2] = red[0];
  __syncthreads();
  float a0 = Araw[0];
  float okf = 1.0f;
  for (int u = 0; u < 16; ++u) {
    int idx = tid * 16 + u;
    int i = idx >> 6, j = idx & 63;
    float v = Araw[idx];
    bool good = (i == j) ? (v == a0) : (v == 0.0f);
    if (!good) okf = 0.0f;
  }
  red[tid] = okf;
  __syncthreads();
  for (int o = 128; o; o >>= 1) {
    if (tid < o) red[tid] = fminf(red[tid], red[tid + o]);
    __syncthreads();
  }
  float isDiag = red[0];
  __syncthreads();
  for (int u = 0; u < 16; ++u) {
    int idx = tid * 16 + u;
    int i = idx >> 6, j = idx & 63;
    float s = 0.f;
    for (int k = 0; k < 64; ++k) s += Araw[k * 64 + i] * Araw[k * 64 + j];
    Bm[i * PIT + j] = s;
  }
  __syncthreads();
  if (tid < 64) {
    vv[tid] = 1.0f;
    float lam = 0.f;
    for (int it = 0; it < 64; ++it) {
      float ui = 0.f;
      for (int k = 0; k < 64; ++k) ui += Bm[tid * PIT + k] * vv[k];
      float s = ui * ui;
      for (int o = 32; o; o >>= 1) s += __shfl_down(s, o);
      float n2 = __shfl(s, 0);
      float nr = sqrtf(fmaxf(n2, 1e-30f));
      vv[tid] = ui / nr;
      lam = nr;
    }
    if (tid == 0) red[0] = lam;
  }
  __syncthreads();
  float sig = sqrtf(fmaxf(red[0], 0.f));
  float scale = 0.98f / (sig + 1e-6f);
  if (tid == 0) {
    hdr[0] = scale * a0;
    hdr[1] = isDiag;
    hdr[3] = sig;
  }
  for (int u = 0; u < 16; ++u) {
    int idx = tid * 16 + u;
    float v = scale * Araw[idx];
    Asc[idx] = v;
    Ab16[idx] = f2bf(v);
  }
}

// ---------------- K1: per-t Woodbury precompute via MFMA ----------------
__global__ __launch_bounds__(512) void k1(const float* __restrict__ obs,
                                          const float* __restrict__ Lam,
                                          const float* __restrict__ logR,
                                          u16* __restrict__ Sg, u16* __restrict__ Gg,
                                          u16* __restrict__ Hg, float* __restrict__ bv,
                                          float* __restrict__ cv, float* __restrict__ aNv) {
  int t = blockIdx.x, tid = threadIdx.x;
  __shared__ __align__(16) u16 Lt[64 * PL];
  __shared__ __align__(16) u16 LtW[64 * PL];
  __shared__ __align__(16) float w1a[NN], w2a[NN], w3a[NN], wya[NN];
  __shared__ __align__(16) float red[512];
  int lane = tid & 63, wv = tid >> 6;
  int ln = lane & 15, q = lane >> 4;

  float cpart = 0.f, apart = 0.f;
  if (tid < NN) {
    float y = obs[(size_t)t * NN + tid];
    float r = expf(logR[tid]);
    float re = r + 1e-4f;
    float w1 = 1.0f / re;
    bool m = (y != y);
    w1a[tid] = w1;
    w2a[tid] = m ? 0.f : w1;
    w3a[tid] = m ? 0.f : r / (re * re);
    wya[tid] = m ? 0.f : (w1 * y);
    cpart = m ? 0.f : (w1 * y * y);
    apart = m ? 0.f : 1.f;
  }
  const float4* Lsrc = (const float4*)(Lam + (size_t)t * NN * KKD);
  for (int u = 0; u < 8; ++u) {
    int fl = u * 512 + tid;
    float4 v = Lsrc[fl];
    int n = fl >> 4, k0 = (fl & 15) * 4;
    Lt[(k0 + 0) * PL + n] = f2bf(v.x);
    Lt[(k0 + 1) * PL + n] = f2bf(v.y);
    Lt[(k0 + 2) * PL + n] = f2bf(v.z);
    Lt[(k0 + 3) * PL + n] = f2bf(v.w);
  }
  __syncthreads();

  const float* Ws[3] = {w1a, w2a, w3a};
  u16* Os[3] = {Sg + (size_t)t * 4096, Gg + (size_t)t * 4096, Hg + (size_t)t * 4096};
#pragma unroll
  for (int m = 0; m < 3; ++m) {
    const float* W = Ws[m];
    for (int u = 0; u < 4; ++u) {
      int fl = u * 512 + tid;
      int row = fl >> 5, c8 = (fl & 31) * 8;
      ushort4 lo = *(const ushort4*)&Lt[row * PL + c8];
      ushort4 hi = *(const ushort4*)&Lt[row * PL + c8 + 4];
      float4 wa = ldF4(&W[c8]);
      float4 wb = ldF4(&W[c8 + 4]);
      ushort4 olo, ohi;
      olo.x = f2bf(bf2f(lo.x) * wa.x); olo.y = f2bf(bf2f(lo.y) * wa.y);
      olo.z = f2bf(bf2f(lo.z) * wa.z); olo.w = f2bf(bf2f(lo.w) * wa.w);
      ohi.x = f2bf(bf2f(hi.x) * wb.x); ohi.y = f2bf(bf2f(hi.y) * wb.y);
      ohi.z = f2bf(bf2f(hi.z) * wb.z); ohi.w = f2bf(bf2f(hi.w) * wb.w);
      *(ushort4*)&LtW[row * PL + c8] = olo;
      *(ushort4*)&LtW[row * PL + c8 + 4] = ohi;
    }
    __syncthreads();
    u16* O = Os[m];
#pragma unroll
    for (int tl = 0; tl < 2; ++tl) {
      int td = wv + tl * 8, ti = td >> 2, tj = td & 3;
      f32x4 acc = {0.f, 0.f, 0.f, 0.f};
#pragma unroll
      for (int n0 = 0; n0 < 256; n0 += 32)
        acc = __builtin_amdgcn_mfma_f32_16x16x32_bf16(
            *(const short8*)&Lt[(ti * 16 + ln) * PL + n0 + q * 8],
            *(const short8*)&LtW[(tj * 16 + ln) * PL + n0 + q * 8], acc, 0, 0, 0);
      int col = tj * 16 + ln, rb = ti * 16 + q * 4;
#pragma unroll
      for (int r = 0; r < 4; ++r) O[(rb + r) * 64 + col] = f2bf(acc[r]);
    }
    __syncthreads();
  }

  {
    int k = tid >> 3, seg = tid & 7;
    float s = 0.f;
    for (int n = seg * 32; n < seg * 32 + 32; n += 4) {
      ushort4 l4 = *(const ushort4*)&Lt[k * PL + n];
      float4 wy = ldF4(&wya[n]);
      s += bf2f(l4.x) * wy.x + bf2f(l4.y) * wy.y + bf2f(l4.z) * wy.z + bf2f(l4.w) * wy.w;
    }
    red[tid] = s;
  }
  __syncthreads();
  if (tid < 64) {
    float acc = 0.f;
#pragma unroll
    for (int s = 0; s < 8; ++s) acc += red[tid * 8 + s];
    bv[(size_t)t * 64 + tid] = acc;
  }
  __syncthreads();
  red[tid] = cpart;
  __syncthreads();
  for (int o = 256; o; o >>= 1) {
    if (tid < o) red[tid] += red[tid + o];
    __syncthreads();
  }
  if (tid == 0) cv[t] = red[0];
  __syncthreads();
  red[tid] = apart;
  __syncthreads();
  for (int o = 256; o; o >>= 1) {
    if (tid < o) red[tid] += red[tid + o];
    __syncthreads();
  }
  if (tid == 0) aNv[t] = red[0];
}

// ---------------- MFMA fragment helpers (16x16x32 bf16) ----------------
__device__ __forceinline__ f32x4 mmLL(const u16* A, const u16* B, int ti, int tj,
                                      int ln, int q, f32x4 acc) {
  int ao = (ti * 16 + ln) * PB + q * 8;
  int bo = (tj * 16 + ln) * PB + q * 8;
#pragma unroll
  for (int k0 = 0; k0 < 64; k0 += 32)
    acc = __builtin_amdgcn_mfma_f32_16x16x32_bf16(*(const short8*)(A + ao + k0),
                                                  *(const short8*)(B + bo + k0), acc, 0, 0, 0);
  return acc;
}
__device__ __forceinline__ f32x4 mmLG(const u16* A, const u16* __restrict__ Bg, int ti,
                                      int tj, int ln, int q, f32x4 acc) {
  int ao = (ti * 16 + ln) * PB + q * 8;
  const u16* bp = Bg + (tj * 16 + ln) * 64 + q * 8;
#pragma unroll
  for (int k0 = 0; k0 < 64; k0 += 32)
    acc = __builtin_amdgcn_mfma_f32_16x16x32_bf16(*(const short8*)(A + ao + k0),
                                                  *(const short8*)(bp + k0), acc, 0, 0, 0);
  return acc;
}
__device__ __forceinline__ f32x4 mmGL(const u16* __restrict__ Ag, const u16* B, int ti,
                                      int tj, int ln, int q, f32x4 acc) {
  const u16* ap = Ag + (ti * 16 + ln) * 64 + q * 8;
  int bo = (tj * 16 + ln) * PB + q * 8;
#pragma unroll
  for (int k0 = 0; k0 < 64; k0 += 32)
    acc = __builtin_amdgcn_mfma_f32_16x16x32_bf16(*(const short8*)(ap + k0),
                                                  *(const short8*)(B + bo + k0), acc, 0, 0, 0);
  return acc;
}
__device__ __forceinline__ void stLDS(u16* Buf, int ti, int tj, int ln, int q, f32x4 v) {
  int col = tj * 16 + ln, rb = ti * 16 + q * 4;
#pragma unroll
  for (int r = 0; r < 4; ++r) Buf[(rb + r) * PB + col] = f2bf(v[r]);
}

// ---------------- K2: one Jacobi sweep (MFMA matmuls + reg-resident GJ) ------
__global__ __launch_bounds__(512) void k2(const u16* __restrict__ Sg, const u16* __restrict__ Gg,
                                          const u16* __restrict__ Hg, const u16* __restrict__ Pin,
                                          u16* __restrict__ Pout, u16* __restrict__ Wout,
                                          float* __restrict__ ldv, const float* __restrict__ hdr,
                                          const float* __restrict__ Qd,
                                          const u16* __restrict__ Ab16, int sweep, int last) {
  int t = blockIdx.x, tid = threadIdx.x;
  int lane = tid & 63, w = tid >> 6;
  int ln = lane & 15, q = lane >> 4;
  int ig = tid >> 4, jg = tid & 15, i0 = 2 * ig, j0 = 4 * jg;

  __shared__ __align__(16) u16 Pp16[64 * PB];
  __shared__ __align__(16) float Ubuf[4608];
  __shared__ __align__(16) u16 XYb[64 * PB];
  __shared__ __align__(16) u16 Wb[64 * PB];
  float* M32 = Ubuf;
  u16* Eb = (u16*)Ubuf;
  u16* Zb = (u16*)Ubuf + 64 * PB;

  float aS = hdr[0];
  bool diag = (hdr[1] != 0.f);

  // ---- Phase A: P_pred -> Pp16 (bf16) ----
  int row = tid >> 3, cg = tid & 7;
  float pv[8];
  if (t == 0) {
#pragma unroll
    for (int u = 0; u < 8; ++u) pv[u] = (cg * 8 + u == row) ? 1.f : 0.f;
  } else if (sweep == 0) {
#pragma unroll
    for (int u = 0; u < 8; ++u) pv[u] = (cg * 8 + u == row) ? 0.15f : 0.f;
  } else {
    uint4 raw = *(const uint4*)(Pin + (size_t)(t - 1) * 4096 + tid * 8);
    pv[0] = bf2f((u16)(raw.x & 0xffff)); pv[1] = bf2f((u16)(raw.x >> 16));
    pv[2] = bf2f((u16)(raw.y & 0xffff)); pv[3] = bf2f((u16)(raw.y >> 16));
    pv[4] = bf2f((u16)(raw.z & 0xffff)); pv[5] = bf2f((u16)(raw.z >> 16));
    pv[6] = bf2f((u16)(raw.w & 0xffff)); pv[7] = bf2f((u16)(raw.w >> 16));
  }
  if (diag) {
    float a2 = aS * aS;
    float qr = Qd[row];
    uint4 o;
    float v0 = a2 * pv[0] + ((cg * 8 + 0 == row) ? qr : 0.f);
    float v1 = a2 * pv[1] + ((cg * 8 + 1 == row) ? qr : 0.f);
    float v2 = a2 * pv[2] + ((cg * 8 + 2 == row) ? qr : 0.f);
    float v3 = a2 * pv[3] + ((cg * 8 + 3 == row) ? qr : 0.f);
    float v4 = a2 * pv[4] + ((cg * 8 + 4 == row) ? qr : 0.f);
    float v5 = a2 * pv[5] + ((cg * 8 + 5 == row) ? qr : 0.f);
    float v6 = a2 * pv[6] + ((cg * 8 + 6 == row) ? qr : 0.f);
    float v7 = a2 * pv[7] + ((cg * 8 + 7 == row) ? qr : 0.f);
    o.x = pack2(v0, v1); o.y = pack2(v2, v3); o.z = pack2(v4, v5); o.w = pack2(v6, v7);
    *(uint4*)&Pp16[row * PB + cg * 8] = o;
  } else {
    uint4 o;
    o.x = pack2(pv[0], pv[1]); o.y = pack2(pv[2], pv[3]);
    o.z = pack2(pv[4], pv[5]); o.w = pack2(pv[6], pv[7]);
    *(uint4*)&Pp16[row * PB + cg * 8] = o;
    __syncthreads();
#pragma unroll
    for (int tl = 0; tl < 2; ++tl) {
      int td = w + tl * 8, ti = td >> 2, tj = td & 3;
      f32x4 acc = {0.f, 0.f, 0.f, 0.f};
      acc = mmGL(Ab16, Pp16, ti, tj, ln, q, acc);
      stLDS(XYb, ti, tj, ln, q, acc);
    }
    __syncthreads();
#pragma unroll
    for (int tl = 0; tl < 2; ++tl) {
      int td = w + tl * 8, ti = td >> 2, tj = td & 3;
      f32x4 acc = {0.f, 0.f, 0.f, 0.f};
      acc = mmLG(XYb, Ab16, ti, tj, ln, q, acc);
      int col = tj * 16 + ln, rb = ti * 16 + q * 4;
#pragma unroll
      for (int r = 0; r < 4; ++r) {
        float v = acc[r] + ((rb + r) == col ? Qd[rb + r] : 0.f);
        Pp16[(rb + r) * PB + col] = f2bf(v);
      }
    }
  }
  __syncthreads();

  // ---- Phase B: M = I + P_pred * S  (fp32 into M32) ----
#pragma unroll
  for (int tl = 0; tl < 2; ++tl) {
    int td = w + tl * 8, ti = td >> 2, tj = td & 3;
    f32x4 acc = {0.f, 0.f, 0.f, 0.f};
    acc = mmLG(Pp16, Sg + (size_t)t * 4096, ti, tj, ln, q, acc);
    int col = tj * 16 + ln, rb = ti * 16 + q * 4;
#pragma unroll
    for (int r = 0; r < 4; ++r) M32[(rb + r) * PIT + col] = acc[r] + ((rb + r) == col ? 1.f : 0.f);
  }
  __syncthreads();

  // ---- Phase C: register-resident Gauss-Jordan ----
  // Thread owns rows i0,i0+1 x cols j0..j0+3 in r0[],r1[]. Pivot row slice
  // read from LDS (row j written by its owner at end of iter j-1); pivot
  // multipliers f0,f1 and pivot value via __shfl from provider lane
  // (lane&48)|g (same wave, same ig group, jg==g). One barrier per iter.
  float r0[4], r1[4];
  {
    float4 a = ldF4(&M32[i0 * PIT + j0]);
    float4 b = ldF4(&M32[(i0 + 1) * PIT + j0]);
    r0[0] = a.x; r0[1] = a.y; r0[2] = a.z; r0[3] = a.w;
    r1[0] = b.x; r1[1] = b.y; r1[2] = b.z; r1[3] = b.w;
  }
  float ldacc = 0.f;
  int provBase = lane & 48;
  for (int g = 0; g < 16; ++g) {
#pragma unroll
    for (int u = 0; u < 4; ++u) {
      int j = g * 4 + u;
      float4 pq = ldF4(&M32[j * PIT + j0]);
      float pr4[4] = {pq.x, pq.y, pq.z, pq.w};
      float piv = __shfl(pr4[u], g);            // lane g holds cols 4g..4g+3 of row j
      float f0 = __shfl(r0[u], provBase + g);   // M[i0][j] from column-owner
      float f1 = __shfl(r1[u], provBase + g);
      float ap = fabsf(piv);
      float pvv = (ap < 1e-12f) ? ((piv < 0.f) ? -1e-12f : 1e-12f) : piv;
      float prc = 1.0f / pvv;
      if (tid == 0) ldacc += logf(fabsf(pvv));
      float fp0 = f0 * prc, fp1 = f1 * prc;
#pragma unroll
      for (int c = 0; c < 4; ++c) {
        r0[c] = fmaf(-fp0, pr4[c], r0[c]);
        r1[c] = fmaf(-fp1, pr4[c], r1[c]);
      }
      if (jg == g) { r0[u] = -fp0; r1[u] = -fp1; }
      int jrow = 2 * g + (u >> 1);              // j>>1
      if (ig == jrow) {
        if ((u & 1) == 0) {
#pragma unroll
          for (int c = 0; c < 4; ++c) r0[c] = pr4[c] * prc;
          if (jg == g) r0[u] = prc;
        } else {
#pragma unroll
          for (int c = 0; c < 4; ++c) r1[c] = pr4[c] * prc;
          if (jg == g) r1[u] = prc;
        }
      }
      // publish row j+1 (its state after this iteration) for next pivot read
      if (j < 63) {
        int jn = j + 1;
        if (i0 == jn)
          *(float4*)&M32[jn * PIT + j0] = make_float4(r0[0], r0[1], r0[2], r0[3]);
        else if (i0 + 1 == jn)
          *(float4*)&M32[jn * PIT + j0] = make_float4(r1[0], r1[1], r1[2], r1[3]);
      }
      __syncthreads();
    }
  }

  // ---- Phase D: pack inverse regs -> XYb (bf16) ----
  {
    ushort4 oa, ob;
    oa.x = f2bf(r0[0]); oa.y = f2bf(r0[1]); oa.z = f2bf(r0[2]); oa.w = f2bf(r0[3]);
    ob.x = f2bf(r1[0]); ob.y = f2bf(r1[1]); ob.z = f2bf(r1[2]); ob.w = f2bf(r1[3]);
    *(ushort4*)&XYb[i0 * PB + j0] = oa;
    *(ushort4*)&XYb[(i0 + 1) * PB + j0] = ob;
  }
  __syncthreads();

  // ---- Phase E: W = X * P_pred^T ----
#pragma unroll
  for (int tl = 0; tl < 2; ++tl) {
    int td = w + tl * 8, ti = td >> 2, tj = td & 3;
    f32x4 acc = {0.f, 0.f, 0.f, 0.f};
    acc = mmLL(XYb, Pp16, ti, tj, ln, q, acc);
    stLDS(Wb, ti, tj, ln, q, acc);
    if (last) {
      int col = tj * 16 + ln, rb = ti * 16 + q * 4;
#pragma unroll
      for (int r = 0; r < 4; ++r)
        Wout[(size_t)t * 4096 + (rb + r) * 64 + col] = f2bf(fin(acc[r]));
    }
  }
  __syncthreads();

  // ---- Phase F: E = I - W*G^T -> Eb ; Z = W*H^T -> Zb ----
#pragma unroll
  for (int tl = 0; tl < 2; ++tl) {
    int td = w + tl * 8, ti = td >> 2, tj = td & 3;
    f32x4 e = {0.f, 0.f, 0.f, 0.f}, z = {0.f, 0.f, 0.f, 0.f};
    e = mmLG(Wb, Gg + (size_t)t * 4096, ti, tj, ln, q, e);
    z = mmLG(Wb, Hg + (size_t)t * 4096, ti, tj, ln, q, z);
    int col = tj * 16 + ln, rb = ti * 16 + q * 4;
#pragma unroll
    for (int r = 0; r < 4; ++r) {
      Eb[(rb + r) * PB + col] = f2bf(((rb + r) == col ? 1.f : 0.f) - e[r]);
      Zb[(rb + r) * PB + col] = f2bf(z[r]);
    }
  }
  __syncthreads();

  // ---- Phase G: C2 = Z*W^T (regs); Y = E*P_pred^T -> XYb ----
  f32x4 c2[2];
#pragma unroll
  for (int tl = 0; tl < 2; ++tl) {
    int td = w + tl * 8, ti = td >> 2, tj = td & 3;
    f32x4 acc = {0.f, 0.f, 0.f, 0.f};
    c2[tl] = mmLL(Zb, Wb, ti, tj, ln, q, acc);
    f32x4 y = {0.f, 0.f, 0.f, 0.f};
    y = mmLL(Eb, Pp16, ti, tj, ln, q, y);
    stLDS(XYb, ti, tj, ln, q, y);
  }
  __syncthreads();

  // ---- Phase H: P_upd = Y*E^T + C2 -> global ----
#pragma unroll
  for (int tl = 0; tl < 2; ++tl) {
    int td = w + tl * 8, ti = td >> 2, tj = td & 3;
    f32x4 acc = c2[tl];
    acc = mmLL(XYb, Eb, ti, tj, ln, q, acc);
    int col = tj * 16 + ln, rb = ti * 16 + q * 4;
#pragma unroll
    for (int r = 0; r < 4; ++r)
      Pout[(size_t)t * 4096 + (rb + r) * 64 + col] = f2bf(fin(acc[r]));
  }
  if (last && tid == 0) ldv[t] = fin(ldacc);
}

// ---------------- K3: state + loglik, chunked parallel with warmup ----------------
#define OWN 4
#define WARM 16
__global__ __launch_bounds__(256) void k3(const u16* __restrict__ Gg, const u16* __restrict__ Wg,
                                          const float* __restrict__ bv, const float* __restrict__ cv,
                                          const float* __restrict__ aNv, const float* __restrict__ ldv,
                                          const float* __restrict__ hdr, const float* __restrict__ Asc,
                                          float* __restrict__ out) {
  int b = blockIdx.x, tid = threadIdx.x;
  int t0 = b * OWN;
  int tw = t0 - WARM;
  if (tw < 0) tw = 0;
  __shared__ __align__(16) float z[64], zp[64], q[64], wv[64], uu[64], part[256];
  float aS = hdr[0];
  bool diag = (hdr[1] != 0.f);
  float slr = hdr[2];
  if (tid < 64) z[tid] = 0.f;
  __syncthreads();
  for (int t = tw; t < t0 + OWN; ++t) {
    bool own = (t >= t0);
    if (tid < 64) {
      if (diag)
        zp[tid] = aS * z[tid];
      else {
        float s = 0.f;
        for (int k = 0; k < 64; k += 4) {
          float4 a = ldF4(&Asc[tid * 64 + k]);
          s += a.x * z[k] + a.y * z[k + 1] + a.z * z[k + 2] + a.w * z[k + 3];
        }
        zp[tid] = s;
      }
    }
    __syncthreads();
    {
      int i = tid & 63, seg = tid >> 6;
      const u16* Gr = Gg + (size_t)t * 4096 + i * 64 + seg * 16;
      float s = 0.f;
      for (int u = 0; u < 16; u += 4) {
        ushort4 g4 = *(const ushort4*)(Gr + u);
        const float* zz = &zp[seg * 16 + u];
        s += bf2f(g4.x) * zz[0] + bf2f(g4.y) * zz[1] + bf2f(g4.z) * zz[2] + bf2f(g4.w) * zz[3];
      }
      part[tid] = s;
    }
    __syncthreads();
    if (tid < 64) {
      float qi = part[tid] + part[tid + 64] + part[tid + 128] + part[tid + 192];
      q[tid] = qi;
      wv[tid] = bv[(size_t)t * 64 + tid] - qi;
    }
    __syncthreads();
    {
      int i = tid & 63, seg = tid >> 6;
      const u16* Wr = Wg + (size_t)t * 4096 + i * 64 + seg * 16;
      float s = 0.f;
      for (int u = 0; u < 16; u += 4) {
        ushort4 g4 = *(const ushort4*)(Wr + u);
        const float* zz = &wv[seg * 16 + u];
        s += bf2f(g4.x) * zz[0] + bf2f(g4.y) * zz[1] + bf2f(g4.z) * zz[2] + bf2f(g4.w) * zz[3];
      }
      part[tid] = s;
    }
    __syncthreads();
    if (tid < 64) {
      float ui = part[tid] + part[tid + 64] + part[tid + 128] + part[tid + 192];
      uu[tid] = ui;
      float zi = zp[tid] + ui;
      z[tid] = isfinite(zi) ? zi : 0.f;
    }
    __syncthreads();
    if (tid < 64) {
      float bz = bv[(size_t)t * 64 + tid] * zp[tid];
      float zq = zp[tid] * q[tid];
      float wu = wv[tid] * uu[tid];
      for (int o = 32; o; o >>= 1) {
        bz += __shfl_down(bz, o);
        zq += __shfl_down(zq, o);
        wu += __shfl_down(wu, o);
      }
      if (tid == 0 && own) {
        float mahal = cv[t] - 2.f * bz + zq - wu;
        float ll = -0.5f * (aNv[t] * LOG2PI + slr + ldv[t] + mahal);
        if (!isfinite(ll)) ll = -1e6f;
        out[(size_t)t * 65 + 64] = ll;
      }
      if (own) out[(size_t)t * 65 + tid] = z[tid];
    }
    __syncthreads();
  }
}

extern "C" void kernel_launch(void* const* d_in, const int* in_sizes, int n_in,
                              void* d_out, int out_size, void* d_ws, size_t ws_size,
                              hipStream_t stream) {
  const float* obs = (const float*)d_in[0];
  const float* Lam = (const float*)d_in[1];
  const float* Araw = (const float*)d_in[2];
  const float* logQ = (const float*)d_in[3];
  const float* logR = (const float*)d_in[4];
  float* out = (float*)d_out;

  char* w = (char*)d_ws;
  float* hdr = (float*)w;
  float* Qd = hdr + 64;
  float* Asc = hdr + 128;
  u16* Ab16 = (u16*)(hdr + 4224);
  const size_t MB = (size_t)TT * 4096;
  u16* Sg = (u16*)(w + 32768);
  u16* Gg = Sg + MB;
  u16* Hg = Gg + MB;
  u16* Wg = Hg + MB;
  u16* Pb0 = Wg + MB;
  u16* Pb1 = Pb0 + MB;
  float* bv = (float*)(Pb1 + MB);
  float* cv = bv + (size_t)TT * 64;
  float* aNv = cv + TT;
  float* ldv = aNv + TT;

  k0<<<dim3(1), dim3(256), 0, stream>>>(Araw, logQ, logR, hdr, Qd, Asc, Ab16);
  k1<<<dim3(TT), dim3(512), 0, stream>>>(obs, Lam, logR, Sg, Gg, Hg, bv, cv, aNv);
  for (int s = 0; s < NSWEEPS; ++s) {
    const u16* pin = (s & 1) ? Pb1 : Pb0;
    u16* pout = (s & 1) ? Pb0 : Pb1;
    k2<<<dim3(TT), dim3(512), 0, stream>>>(Sg, Gg, Hg, pin, pout, Wg, ldv, hdr, Qd, Ab16, s,
                                           (s == NSWEEPS - 1) ? 1 : 0);
  }
  k3<<<dim3(TT / OWN), dim3(256), 0, stream>>>(Gg, Wg, bv, cv, aNv, ldv, hdr, Asc, out);
}

// Round 6
// 701.084 us; speedup vs baseline: 6.4386x; 1.1422x over previous
//
#include <hip/hip_runtime.h>

// LTV Kalman filter, GPU-restructured (Woodbury + parallel Jacobi-Riccati).
// R6: k2 processes 2 consecutive t per block (Gauss-Seidel within block:
// step 2 uses step 1's P straight from LDS), 2 sweeps (truth depth 3-4 =
// old 4 Jacobi sweeps; contraction ~0.026/step); Pout only odd t on
// non-last sweeps. k3: OWN=2, WARM=10.

#define TT 2048
#define NN 256
#define KKD 64
#define PIT 68      // fp32 LDS pitch
#define PB 72       // bf16 LDS pitch (k2 64x64 tiles)
#define PL 264      // bf16 LDS pitch for k1 64x256 L^T tiles
#define NSWEEPS 2
#define LOG2PI 1.8378770664093453f

typedef unsigned short u16;
typedef unsigned int u32;
typedef __attribute__((ext_vector_type(8))) short short8;
typedef __attribute__((ext_vector_type(4))) float f32x4;

__device__ __forceinline__ float bf2f(u16 u) {
  u32 x = ((u32)u) << 16;
  return __uint_as_float(x);
}
__device__ __forceinline__ u16 f2bf(float f) {
  u32 u = __float_as_uint(f);
  u32 r = (u + 0x7fffu + ((u >> 16) & 1u)) >> 16;
  return (u16)r;
}
__device__ __forceinline__ u32 pack2(float a, float b) {
  return (u32)f2bf(a) | ((u32)f2bf(b) << 16);
}
__device__ __forceinline__ float4 ldF4(const float* p) { return *(const float4*)p; }
__device__ __forceinline__ float fin(float v) { return isfinite(v) ? v : 0.f; }

// ---------------- K0: scalars ----------------
__global__ __launch_bounds__(256) void k0(const float* __restrict__ Araw,
                                          const float* __restrict__ logQ,
                                          const float* __restrict__ logR,
                                          float* hdr, float* Qd, float* Asc, u16* Ab16) {
  __shared__ __align__(16) float Bm[64 * PIT];
  __shared__ __align__(16) float red[256];
  __shared__ __align__(16) float vv[64];
  int tid = threadIdx.x;
  if (tid < 64) Qd[tid] = expf(logQ[tid]);
  float r = expf(logR[tid]);
  red[tid] = logf(r + 1e-4f);
  __syncthreads();
  for (int o = 128; o; o >>= 1) {
    if (tid < o) red[tid] += red[tid + o];
    __syncthreads();
  }
  if (tid == 0) hdr[2] = red[0];
  __syncthreads();
  float a0 = Araw[0];
  float okf = 1.0f;
  for (int u = 0; u < 16; ++u) {
    int idx = tid * 16 + u;
    int i = idx >> 6, j = idx & 63;
    float v = Araw[idx];
    bool good = (i == j) ? (v == a0) : (v == 0.0f);
    if (!good) okf = 0.0f;
  }
  red[tid] = okf;
  __syncthreads();
  for (int o = 128; o; o >>= 1) {
    if (tid < o) red[tid] = fminf(red[tid], red[tid + o]);
    __syncthreads();
  }
  float isDiag = red[0];
  __syncthreads();
  for (int u = 0; u < 16; ++u) {
    int idx = tid * 16 + u;
    int i = idx >> 6, j = idx & 63;
    float s = 0.f;
    for (int k = 0; k < 64; ++k) s += Araw[k * 64 + i] * Araw[k * 64 + j];
    Bm[i * PIT + j] = s;
  }
  __syncthreads();
  if (tid < 64) {
    vv[tid] = 1.0f;
    float lam = 0.f;
    for (int it = 0; it < 64; ++it) {
      float ui = 0.f;
      for (int k = 0; k < 64; ++k) ui += Bm[tid * PIT + k] * vv[k];
      float s = ui * ui;
      for (int o = 32; o; o >>= 1) s += __shfl_down(s, o);
      float n2 = __shfl(s, 0);
      float nr = sqrtf(fmaxf(n2, 1e-30f));
      vv[tid] = ui / nr;
      lam = nr;
    }
    if (tid == 0) red[0] = lam;
  }
  __syncthreads();
  float sig = sqrtf(fmaxf(red[0], 0.f));
  float scale = 0.98f / (sig + 1e-6f);
  if (tid == 0) {
    hdr[0] = scale * a0;
    hdr[1] = isDiag;
    hdr[3] = sig;
  }
  for (int u = 0; u < 16; ++u) {
    int idx = tid * 16 + u;
    float v = scale * Araw[idx];
    Asc[idx] = v;
    Ab16[idx] = f2bf(v);
  }
}

// ---------------- K1: per-t Woodbury precompute via MFMA ----------------
__global__ __launch_bounds__(512) void k1(const float* __restrict__ obs,
                                          const float* __restrict__ Lam,
                                          const float* __restrict__ logR,
                                          u16* __restrict__ Sg, u16* __restrict__ Gg,
                                          u16* __restrict__ Hg, float* __restrict__ bv,
                                          float* __restrict__ cv, float* __restrict__ aNv) {
  int t = blockIdx.x, tid = threadIdx.x;
  __shared__ __align__(16) u16 Lt[64 * PL];
  __shared__ __align__(16) u16 LtW[64 * PL];
  __shared__ __align__(16) float w1a[NN], w2a[NN], w3a[NN], wya[NN];
  __shared__ __align__(16) float red[512];
  int lane = tid & 63, wv = tid >> 6;
  int ln = lane & 15, q = lane >> 4;

  float cpart = 0.f, apart = 0.f;
  if (tid < NN) {
    float y = obs[(size_t)t * NN + tid];
    float r = expf(logR[tid]);
    float re = r + 1e-4f;
    float w1 = 1.0f / re;
    bool m = (y != y);
    w1a[tid] = w1;
    w2a[tid] = m ? 0.f : w1;
    w3a[tid] = m ? 0.f : r / (re * re);
    wya[tid] = m ? 0.f : (w1 * y);
    cpart = m ? 0.f : (w1 * y * y);
    apart = m ? 0.f : 1.f;
  }
  const float4* Lsrc = (const float4*)(Lam + (size_t)t * NN * KKD);
  for (int u = 0; u < 8; ++u) {
    int fl = u * 512 + tid;
    float4 v = Lsrc[fl];
    int n = fl >> 4, k0 = (fl & 15) * 4;
    Lt[(k0 + 0) * PL + n] = f2bf(v.x);
    Lt[(k0 + 1) * PL + n] = f2bf(v.y);
    Lt[(k0 + 2) * PL + n] = f2bf(v.z);
    Lt[(k0 + 3) * PL + n] = f2bf(v.w);
  }
  __syncthreads();

  const float* Ws[3] = {w1a, w2a, w3a};
  u16* Os[3] = {Sg + (size_t)t * 4096, Gg + (size_t)t * 4096, Hg + (size_t)t * 4096};
#pragma unroll
  for (int m = 0; m < 3; ++m) {
    const float* W = Ws[m];
    for (int u = 0; u < 4; ++u) {
      int fl = u * 512 + tid;
      int row = fl >> 5, c8 = (fl & 31) * 8;
      ushort4 lo = *(const ushort4*)&Lt[row * PL + c8];
      ushort4 hi = *(const ushort4*)&Lt[row * PL + c8 + 4];
      float4 wa = ldF4(&W[c8]);
      float4 wb = ldF4(&W[c8 + 4]);
      ushort4 olo, ohi;
      olo.x = f2bf(bf2f(lo.x) * wa.x); olo.y = f2bf(bf2f(lo.y) * wa.y);
      olo.z = f2bf(bf2f(lo.z) * wa.z); olo.w = f2bf(bf2f(lo.w) * wa.w);
      ohi.x = f2bf(bf2f(hi.x) * wb.x); ohi.y = f2bf(bf2f(hi.y) * wb.y);
      ohi.z = f2bf(bf2f(hi.z) * wb.z); ohi.w = f2bf(bf2f(hi.w) * wb.w);
      *(ushort4*)&LtW[row * PL + c8] = olo;
      *(ushort4*)&LtW[row * PL + c8 + 4] = ohi;
    }
    __syncthreads();
    u16* O = Os[m];
#pragma unroll
    for (int tl = 0; tl < 2; ++tl) {
      int td = wv + tl * 8, ti = td >> 2, tj = td & 3;
      f32x4 acc = {0.f, 0.f, 0.f, 0.f};
#pragma unroll
      for (int n0 = 0; n0 < 256; n0 += 32)
        acc = __builtin_amdgcn_mfma_f32_16x16x32_bf16(
            *(const short8*)&Lt[(ti * 16 + ln) * PL + n0 + q * 8],
            *(const short8*)&LtW[(tj * 16 + ln) * PL + n0 + q * 8], acc, 0, 0, 0);
      int col = tj * 16 + ln, rb = ti * 16 + q * 4;
#pragma unroll
      for (int r = 0; r < 4; ++r) O[(rb + r) * 64 + col] = f2bf(acc[r]);
    }
    __syncthreads();
  }

  {
    int k = tid >> 3, seg = tid & 7;
    float s = 0.f;
    for (int n = seg * 32; n < seg * 32 + 32; n += 4) {
      ushort4 l4 = *(const ushort4*)&Lt[k * PL + n];
      float4 wy = ldF4(&wya[n]);
      s += bf2f(l4.x) * wy.x + bf2f(l4.y) * wy.y + bf2f(l4.z) * wy.z + bf2f(l4.w) * wy.w;
    }
    red[tid] = s;
  }
  __syncthreads();
  if (tid < 64) {
    float acc = 0.f;
#pragma unroll
    for (int s = 0; s < 8; ++s) acc += red[tid * 8 + s];
    bv[(size_t)t * 64 + tid] = acc;
  }
  __syncthreads();
  red[tid] = cpart;
  __syncthreads();
  for (int o = 256; o; o >>= 1) {
    if (tid < o) red[tid] += red[tid + o];
    __syncthreads();
  }
  if (tid == 0) cv[t] = red[0];
  __syncthreads();
  red[tid] = apart;
  __syncthreads();
  for (int o = 256; o; o >>= 1) {
    if (tid < o) red[tid] += red[tid + o];
    __syncthreads();
  }
  if (tid == 0) aNv[t] = red[0];
}

// ---------------- MFMA fragment helpers (16x16x32 bf16) ----------------
__device__ __forceinline__ f32x4 mmLL(const u16* A, const u16* B, int ti, int tj,
                                      int ln, int q, f32x4 acc) {
  int ao = (ti * 16 + ln) * PB + q * 8;
  int bo = (tj * 16 + ln) * PB + q * 8;
#pragma unroll
  for (int k0 = 0; k0 < 64; k0 += 32)
    acc = __builtin_amdgcn_mfma_f32_16x16x32_bf16(*(const short8*)(A + ao + k0),
                                                  *(const short8*)(B + bo + k0), acc, 0, 0, 0);
  return acc;
}
__device__ __forceinline__ f32x4 mmLG(const u16* A, const u16* __restrict__ Bg, int ti,
                                      int tj, int ln, int q, f32x4 acc) {
  int ao = (ti * 16 + ln) * PB + q * 8;
  const u16* bp = Bg + (tj * 16 + ln) * 64 + q * 8;
#pragma unroll
  for (int k0 = 0; k0 < 64; k0 += 32)
    acc = __builtin_amdgcn_mfma_f32_16x16x32_bf16(*(const short8*)(A + ao + k0),
                                                  *(const short8*)(bp + k0), acc, 0, 0, 0);
  return acc;
}
__device__ __forceinline__ f32x4 mmGL(const u16* __restrict__ Ag, const u16* B, int ti,
                                      int tj, int ln, int q, f32x4 acc) {
  const u16* ap = Ag + (ti * 16 + ln) * 64 + q * 8;
  int bo = (tj * 16 + ln) * PB + q * 8;
#pragma unroll
  for (int k0 = 0; k0 < 64; k0 += 32)
    acc = __builtin_amdgcn_mfma_f32_16x16x32_bf16(*(const short8*)(ap + k0),
                                                  *(const short8*)(B + bo + k0), acc, 0, 0, 0);
  return acc;
}
__device__ __forceinline__ void stLDS(u16* Buf, int ti, int tj, int ln, int q, f32x4 v) {
  int col = tj * 16 + ln, rb = ti * 16 + q * 4;
#pragma unroll
  for (int r = 0; r < 4; ++r) Buf[(rb + r) * PB + col] = f2bf(v[r]);
}

// ---------------- K2: two GS-chained Riccati steps per block ------
__global__ __launch_bounds__(512) void k2(const u16* __restrict__ Sg, const u16* __restrict__ Gg,
                                          const u16* __restrict__ Hg, const u16* __restrict__ Pin,
                                          u16* __restrict__ Pout, u16* __restrict__ Wout,
                                          float* __restrict__ ldv, const float* __restrict__ hdr,
                                          const float* __restrict__ Qd,
                                          const u16* __restrict__ Ab16, int sweep, int last) {
  int t0 = blockIdx.x * 2, tid = threadIdx.x;
  int lane = tid & 63, w = tid >> 6;
  int ln = lane & 15, q = lane >> 4;
  int ig = tid >> 4, jg = tid & 15, i0 = 2 * ig, j0 = 4 * jg;

  __shared__ __align__(16) u16 Pp16[64 * PB];
  __shared__ __align__(16) float Ubuf[4608];
  __shared__ __align__(16) u16 XYb[64 * PB];
  __shared__ __align__(16) u16 Wb[64 * PB];
  float* M32 = Ubuf;
  u16* Eb = (u16*)Ubuf;
  u16* Zb = (u16*)Ubuf + 64 * PB;

  float aS = hdr[0];
  bool diag = (hdr[1] != 0.f);
  int row = tid >> 3, cg = tid & 7;

  for (int st = 0; st < 2; ++st) {
    int t = t0 + st;

    // ---- Phase A: P_pred -> Pp16 (bf16) ----
    if (st == 0) {
      float pv[8];
      if (t == 0) {
#pragma unroll
        for (int u = 0; u < 8; ++u) pv[u] = (cg * 8 + u == row) ? 1.f : 0.f;
      } else if (sweep == 0) {
#pragma unroll
        for (int u = 0; u < 8; ++u) pv[u] = (cg * 8 + u == row) ? 0.15f : 0.f;
      } else {
        uint4 raw = *(const uint4*)(Pin + (size_t)(t - 1) * 4096 + tid * 8);
        pv[0] = bf2f((u16)(raw.x & 0xffff)); pv[1] = bf2f((u16)(raw.x >> 16));
        pv[2] = bf2f((u16)(raw.y & 0xffff)); pv[3] = bf2f((u16)(raw.y >> 16));
        pv[4] = bf2f((u16)(raw.z & 0xffff)); pv[5] = bf2f((u16)(raw.z >> 16));
        pv[6] = bf2f((u16)(raw.w & 0xffff)); pv[7] = bf2f((u16)(raw.w >> 16));
      }
      if (diag) {
        float a2 = aS * aS;
        float qr = Qd[row];
        uint4 o;
        float v0 = a2 * pv[0] + ((cg * 8 + 0 == row) ? qr : 0.f);
        float v1 = a2 * pv[1] + ((cg * 8 + 1 == row) ? qr : 0.f);
        float v2 = a2 * pv[2] + ((cg * 8 + 2 == row) ? qr : 0.f);
        float v3 = a2 * pv[3] + ((cg * 8 + 3 == row) ? qr : 0.f);
        float v4 = a2 * pv[4] + ((cg * 8 + 4 == row) ? qr : 0.f);
        float v5 = a2 * pv[5] + ((cg * 8 + 5 == row) ? qr : 0.f);
        float v6 = a2 * pv[6] + ((cg * 8 + 6 == row) ? qr : 0.f);
        float v7 = a2 * pv[7] + ((cg * 8 + 7 == row) ? qr : 0.f);
        o.x = pack2(v0, v1); o.y = pack2(v2, v3); o.z = pack2(v4, v5); o.w = pack2(v6, v7);
        *(uint4*)&Pp16[row * PB + cg * 8] = o;
      } else {
        uint4 o;
        o.x = pack2(pv[0], pv[1]); o.y = pack2(pv[2], pv[3]);
        o.z = pack2(pv[4], pv[5]); o.w = pack2(pv[6], pv[7]);
        *(uint4*)&Pp16[row * PB + cg * 8] = o;
        __syncthreads();
#pragma unroll
        for (int tl = 0; tl < 2; ++tl) {
          int td = w + tl * 8, ti = td >> 2, tj = td & 3;
          f32x4 acc = {0.f, 0.f, 0.f, 0.f};
          acc = mmGL(Ab16, Pp16, ti, tj, ln, q, acc);
          stLDS(XYb, ti, tj, ln, q, acc);
        }
        __syncthreads();
#pragma unroll
        for (int tl = 0; tl < 2; ++tl) {
          int td = w + tl * 8, ti = td >> 2, tj = td & 3;
          f32x4 acc = {0.f, 0.f, 0.f, 0.f};
          acc = mmLG(XYb, Ab16, ti, tj, ln, q, acc);
          int col = tj * 16 + ln, rb = ti * 16 + q * 4;
#pragma unroll
          for (int r = 0; r < 4; ++r) {
            float v = acc[r] + ((rb + r) == col ? Qd[rb + r] : 0.f);
            Pp16[(rb + r) * PB + col] = f2bf(v);
          }
        }
      }
    } else {
      // P_prev (posterior of t-1) already in Pp16 from step 1's Phase H.
      if (diag) {
        float a2 = aS * aS;
        float qr = Qd[row];
        uint4 raw = *(const uint4*)&Pp16[row * PB + cg * 8];
        float pv[8];
        pv[0] = bf2f((u16)(raw.x & 0xffff)); pv[1] = bf2f((u16)(raw.x >> 16));
        pv[2] = bf2f((u16)(raw.y & 0xffff)); pv[3] = bf2f((u16)(raw.y >> 16));
        pv[4] = bf2f((u16)(raw.z & 0xffff)); pv[5] = bf2f((u16)(raw.z >> 16));
        pv[6] = bf2f((u16)(raw.w & 0xffff)); pv[7] = bf2f((u16)(raw.w >> 16));
        uint4 o;
        float v0 = a2 * pv[0] + ((cg * 8 + 0 == row) ? qr : 0.f);
        float v1 = a2 * pv[1] + ((cg * 8 + 1 == row) ? qr : 0.f);
        float v2 = a2 * pv[2] + ((cg * 8 + 2 == row) ? qr : 0.f);
        float v3 = a2 * pv[3] + ((cg * 8 + 3 == row) ? qr : 0.f);
        float v4 = a2 * pv[4] + ((cg * 8 + 4 == row) ? qr : 0.f);
        float v5 = a2 * pv[5] + ((cg * 8 + 5 == row) ? qr : 0.f);
        float v6 = a2 * pv[6] + ((cg * 8 + 6 == row) ? qr : 0.f);
        float v7 = a2 * pv[7] + ((cg * 8 + 7 == row) ? qr : 0.f);
        o.x = pack2(v0, v1); o.y = pack2(v2, v3); o.z = pack2(v4, v5); o.w = pack2(v6, v7);
        *(uint4*)&Pp16[row * PB + cg * 8] = o;
      } else {
#pragma unroll
        for (int tl = 0; tl < 2; ++tl) {
          int td = w + tl * 8, ti = td >> 2, tj = td & 3;
          f32x4 acc = {0.f, 0.f, 0.f, 0.f};
          acc = mmGL(Ab16, Pp16, ti, tj, ln, q, acc);
          stLDS(XYb, ti, tj, ln, q, acc);
        }
        __syncthreads();
#pragma unroll
        for (int tl = 0; tl < 2; ++tl) {
          int td = w + tl * 8, ti = td >> 2, tj = td & 3;
          f32x4 acc = {0.f, 0.f, 0.f, 0.f};
          acc = mmLG(XYb, Ab16, ti, tj, ln, q, acc);
          int col = tj * 16 + ln, rb = ti * 16 + q * 4;
#pragma unroll
          for (int r = 0; r < 4; ++r) {
            float v = acc[r] + ((rb + r) == col ? Qd[rb + r] : 0.f);
            Pp16[(rb + r) * PB + col] = f2bf(v);
          }
        }
      }
    }
    __syncthreads();

    // ---- Phase B: M = I + P_pred * S  (fp32 into M32) ----
#pragma unroll
    for (int tl = 0; tl < 2; ++tl) {
      int td = w + tl * 8, ti = td >> 2, tj = td & 3;
      f32x4 acc = {0.f, 0.f, 0.f, 0.f};
      acc = mmLG(Pp16, Sg + (size_t)t * 4096, ti, tj, ln, q, acc);
      int col = tj * 16 + ln, rb = ti * 16 + q * 4;
#pragma unroll
      for (int r = 0; r < 4; ++r)
        M32[(rb + r) * PIT + col] = acc[r] + ((rb + r) == col ? 1.f : 0.f);
    }
    __syncthreads();

    // ---- Phase C: register-resident Gauss-Jordan ----
    float r0[4], r1[4];
    {
      float4 a = ldF4(&M32[i0 * PIT + j0]);
      float4 b = ldF4(&M32[(i0 + 1) * PIT + j0]);
      r0[0] = a.x; r0[1] = a.y; r0[2] = a.z; r0[3] = a.w;
      r1[0] = b.x; r1[1] = b.y; r1[2] = b.z; r1[3] = b.w;
    }
    float ldacc = 0.f;
    int provBase = lane & 48;
    for (int g = 0; g < 16; ++g) {
#pragma unroll
      for (int u = 0; u < 4; ++u) {
        int j = g * 4 + u;
        float4 pq = ldF4(&M32[j * PIT + j0]);
        float pr4[4] = {pq.x, pq.y, pq.z, pq.w};
        float piv = __shfl(pr4[u], g);
        float f0 = __shfl(r0[u], provBase + g);
        float f1 = __shfl(r1[u], provBase + g);
        float ap = fabsf(piv);
        float pvv = (ap < 1e-12f) ? ((piv < 0.f) ? -1e-12f : 1e-12f) : piv;
        float prc = 1.0f / pvv;
        if (tid == 0) ldacc += logf(fabsf(pvv));
        float fp0 = f0 * prc, fp1 = f1 * prc;
#pragma unroll
        for (int c = 0; c < 4; ++c) {
          r0[c] = fmaf(-fp0, pr4[c], r0[c]);
          r1[c] = fmaf(-fp1, pr4[c], r1[c]);
        }
        if (jg == g) { r0[u] = -fp0; r1[u] = -fp1; }
        int jrow = 2 * g + (u >> 1);
        if (ig == jrow) {
          if ((u & 1) == 0) {
#pragma unroll
            for (int c = 0; c < 4; ++c) r0[c] = pr4[c] * prc;
            if (jg == g) r0[u] = prc;
          } else {
#pragma unroll
            for (int c = 0; c < 4; ++c) r1[c] = pr4[c] * prc;
            if (jg == g) r1[u] = prc;
          }
        }
        if (j < 63) {
          int jn = j + 1;
          if (i0 == jn)
            *(float4*)&M32[jn * PIT + j0] = make_float4(r0[0], r0[1], r0[2], r0[3]);
          else if (i0 + 1 == jn)
            *(float4*)&M32[jn * PIT + j0] = make_float4(r1[0], r1[1], r1[2], r1[3]);
        }
        __syncthreads();
      }
    }

    // ---- Phase D: pack inverse regs -> XYb (bf16) ----
    {
      ushort4 oa, ob;
      oa.x = f2bf(r0[0]); oa.y = f2bf(r0[1]); oa.z = f2bf(r0[2]); oa.w = f2bf(r0[3]);
      ob.x = f2bf(r1[0]); ob.y = f2bf(r1[1]); ob.z = f2bf(r1[2]); ob.w = f2bf(r1[3]);
      *(ushort4*)&XYb[i0 * PB + j0] = oa;
      *(ushort4*)&XYb[(i0 + 1) * PB + j0] = ob;
    }
    __syncthreads();

    // ---- Phase E: W = X * P_pred^T ----
#pragma unroll
    for (int tl = 0; tl < 2; ++tl) {
      int td = w + tl * 8, ti = td >> 2, tj = td & 3;
      f32x4 acc = {0.f, 0.f, 0.f, 0.f};
      acc = mmLL(XYb, Pp16, ti, tj, ln, q, acc);
      stLDS(Wb, ti, tj, ln, q, acc);
      if (last) {
        int col = tj * 16 + ln, rb = ti * 16 + q * 4;
#pragma unroll
        for (int r = 0; r < 4; ++r)
          Wout[(size_t)t * 4096 + (rb + r) * 64 + col] = f2bf(fin(acc[r]));
      }
    }
    __syncthreads();

    // ---- Phase F: E = I - W*G^T -> Eb ; Z = W*H^T -> Zb ----
#pragma unroll
    for (int tl = 0; tl < 2; ++tl) {
      int td = w + tl * 8, ti = td >> 2, tj = td & 3;
      f32x4 e = {0.f, 0.f, 0.f, 0.f}, z = {0.f, 0.f, 0.f, 0.f};
      e = mmLG(Wb, Gg + (size_t)t * 4096, ti, tj, ln, q, e);
      z = mmLG(Wb, Hg + (size_t)t * 4096, ti, tj, ln, q, z);
      int col = tj * 16 + ln, rb = ti * 16 + q * 4;
#pragma unroll
      for (int r = 0; r < 4; ++r) {
        Eb[(rb + r) * PB + col] = f2bf(((rb + r) == col ? 1.f : 0.f) - e[r]);
        Zb[(rb + r) * PB + col] = f2bf(z[r]);
      }
    }
    __syncthreads();

    // ---- Phase G: C2 = Z*W^T (regs); Y = E*P_pred^T -> XYb ----
    f32x4 c2[2];
#pragma unroll
    for (int tl = 0; tl < 2; ++tl) {
      int td = w + tl * 8, ti = td >> 2, tj = td & 3;
      f32x4 acc = {0.f, 0.f, 0.f, 0.f};
      c2[tl] = mmLL(Zb, Wb, ti, tj, ln, q, acc);
      f32x4 y = {0.f, 0.f, 0.f, 0.f};
      y = mmLL(Eb, Pp16, ti, tj, ln, q, y);
      stLDS(XYb, ti, tj, ln, q, y);
    }
    __syncthreads();

    // ---- Phase H: P_upd = Y*E^T + C2 -> Pp16 (and global for odd t, non-last) ----
    f32x4 pacc[2];
#pragma unroll
    for (int tl = 0; tl < 2; ++tl) {
      int td = w + tl * 8, ti = td >> 2, tj = td & 3;
      f32x4 acc = c2[tl];
      acc = mmLL(XYb, Eb, ti, tj, ln, q, acc);
      pacc[tl] = acc;
      if (st == 1 && !last) {
        int col = tj * 16 + ln, rb = ti * 16 + q * 4;
#pragma unroll
        for (int r = 0; r < 4; ++r)
          Pout[(size_t)t * 4096 + (rb + r) * 64 + col] = f2bf(fin(acc[r]));
      }
    }
    if (last && tid == 0) ldv[t] = fin(ldacc);
    if (st == 0) {
      __syncthreads();  // all reads of Pp16 (Phase G) done; safe to overwrite
#pragma unroll
      for (int tl = 0; tl < 2; ++tl) {
        int td = w + tl * 8, ti = td >> 2, tj = td & 3;
        int col = tj * 16 + ln, rb = ti * 16 + q * 4;
#pragma unroll
        for (int r = 0; r < 4; ++r)
          Pp16[(rb + r) * PB + col] = f2bf(fin(pacc[tl][r]));
      }
      __syncthreads();
    }
  }
}

// ---------------- K3: state + loglik, chunked parallel with warmup ----------------
#define OWN 2
#define WARM 10
__global__ __launch_bounds__(256) void k3(const u16* __restrict__ Gg, const u16* __restrict__ Wg,
                                          const float* __restrict__ bv, const float* __restrict__ cv,
                                          const float* __restrict__ aNv, const float* __restrict__ ldv,
                                          const float* __restrict__ hdr, const float* __restrict__ Asc,
                                          float* __restrict__ out) {
  int b = blockIdx.x, tid = threadIdx.x;
  int t0 = b * OWN;
  int tw = t0 - WARM;
  if (tw < 0) tw = 0;
  __shared__ __align__(16) float z[64], zp[64], q[64], wv[64], uu[64], part[256];
  float aS = hdr[0];
  bool diag = (hdr[1] != 0.f);
  float slr = hdr[2];
  if (tid < 64) z[tid] = 0.f;
  __syncthreads();
  for (int t = tw; t < t0 + OWN; ++t) {
    bool own = (t >= t0);
    if (tid < 64) {
      if (diag)
        zp[tid] = aS * z[tid];
      else {
        float s = 0.f;
        for (int k = 0; k < 64; k += 4) {
          float4 a = ldF4(&Asc[tid * 64 + k]);
          s += a.x * z[k] + a.y * z[k + 1] + a.z * z[k + 2] + a.w * z[k + 3];
        }
        zp[tid] = s;
      }
    }
    __syncthreads();
    {
      int i = tid & 63, seg = tid >> 6;
      const u16* Gr = Gg + (size_t)t * 4096 + i * 64 + seg * 16;
      float s = 0.f;
      for (int u = 0; u < 16; u += 4) {
        ushort4 g4 = *(const ushort4*)(Gr + u);
        const float* zz = &zp[seg * 16 + u];
        s += bf2f(g4.x) * zz[0] + bf2f(g4.y) * zz[1] + bf2f(g4.z) * zz[2] + bf2f(g4.w) * zz[3];
      }
      part[tid] = s;
    }
    __syncthreads();
    if (tid < 64) {
      float qi = part[tid] + part[tid + 64] + part[tid + 128] + part[tid + 192];
      q[tid] = qi;
      wv[tid] = bv[(size_t)t * 64 + tid] - qi;
    }
    __syncthreads();
    {
      int i = tid & 63, seg = tid >> 6;
      const u16* Wr = Wg + (size_t)t * 4096 + i * 64 + seg * 16;
      float s = 0.f;
      for (int u = 0; u < 16; u += 4) {
        ushort4 g4 = *(const ushort4*)(Wr + u);
        const float* zz = &wv[seg * 16 + u];
        s += bf2f(g4.x) * zz[0] + bf2f(g4.y) * zz[1] + bf2f(g4.z) * zz[2] + bf2f(g4.w) * zz[3];
      }
      part[tid] = s;
    }
    __syncthreads();
    if (tid < 64) {
      float ui = part[tid] + part[tid + 64] + part[tid + 128] + part[tid + 192];
      uu[tid] = ui;
      float zi = zp[tid] + ui;
      z[tid] = isfinite(zi) ? zi : 0.f;
    }
    __syncthreads();
    if (tid < 64) {
      float bz = bv[(size_t)t * 64 + tid] * zp[tid];
      float zq = zp[tid] * q[tid];
      float wu = wv[tid] * uu[tid];
      for (int o = 32; o; o >>= 1) {
        bz += __shfl_down(bz, o);
        zq += __shfl_down(zq, o);
        wu += __shfl_down(wu, o);
      }
      if (tid == 0 && own) {
        float mahal = cv[t] - 2.f * bz + zq - wu;
        float ll = -0.5f * (aNv[t] * LOG2PI + slr + ldv[t] + mahal);
        if (!isfinite(ll)) ll = -1e6f;
        out[(size_t)t * 65 + 64] = ll;
      }
      if (own) out[(size_t)t * 65 + tid] = z[tid];
    }
    __syncthreads();
  }
}

extern "C" void kernel_launch(void* const* d_in, const int* in_sizes, int n_in,
                              void* d_out, int out_size, void* d_ws, size_t ws_size,
                              hipStream_t stream) {
  const float* obs = (const float*)d_in[0];
  const float* Lam = (const float*)d_in[1];
  const float* Araw = (const float*)d_in[2];
  const float* logQ = (const float*)d_in[3];
  const float* logR = (const float*)d_in[4];
  float* out = (float*)d_out;

  char* w = (char*)d_ws;
  float* hdr = (float*)w;
  float* Qd = hdr + 64;
  float* Asc = hdr + 128;
  u16* Ab16 = (u16*)(hdr + 4224);
  const size_t MB = (size_t)TT * 4096;
  u16* Sg = (u16*)(w + 32768);
  u16* Gg = Sg + MB;
  u16* Hg = Gg + MB;
  u16* Wg = Hg + MB;
  u16* Pb0 = Wg + MB;
  float* bv = (float*)(Pb0 + MB);
  float* cv = bv + (size_t)TT * 64;
  float* aNv = cv + TT;
  float* ldv = aNv + TT;

  k0<<<dim3(1), dim3(256), 0, stream>>>(Araw, logQ, logR, hdr, Qd, Asc, Ab16);
  k1<<<dim3(TT), dim3(512), 0, stream>>>(obs, Lam, logR, Sg, Gg, Hg, bv, cv, aNv);
  for (int s = 0; s < NSWEEPS; ++s) {
    k2<<<dim3(TT / 2), dim3(512), 0, stream>>>(Sg, Gg, Hg, Pb0, Pb0, Wg, ldv, hdr, Qd, Ab16, s,
                                               (s == NSWEEPS - 1) ? 1 : 0);
  }
  k3<<<dim3(TT / OWN), dim3(256), 0, stream>>>(Gg, Wg, bv, cv, aNv, ldv, hdr, Asc, out);
}

// Round 7
// 478.502 us; speedup vs baseline: 9.4336x; 1.4652x over previous
//
#include <hip/hip_runtime.h>

// LTV Kalman filter, GPU-restructured (Woodbury + parallel Riccati).
// R7: H==G (r/(r+1e-4) uniform => below bf16) -> Hg dropped everywhere.
// Sweep 1 (k2a): GS-paired, inverse via MFMA Newton (9 it, power-iter alpha),
// P_upd = W = M^-1 P_pred (short form; error contracts x0.07 in final sweep).
// Final sweep (k2b): exact reg-GJ + logdet, phases A-E only (P never consumed).
// k3: OWN=4, WARM=12.

#define TT 2048
#define NN 256
#define KKD 64
#define PIT 68      // fp32 LDS pitch
#define PB 72       // bf16 LDS pitch
#define PL 264      // bf16 LDS pitch for k1 64x256 L^T tiles
#define LOG2PI 1.8378770664093453f

typedef unsigned short u16;
typedef unsigned int u32;
typedef __attribute__((ext_vector_type(8))) short short8;
typedef __attribute__((ext_vector_type(4))) float f32x4;

__device__ __forceinline__ float bf2f(u16 u) {
  u32 x = ((u32)u) << 16;
  return __uint_as_float(x);
}
__device__ __forceinline__ u16 f2bf(float f) {
  u32 u = __float_as_uint(f);
  u32 r = (u + 0x7fffu + ((u >> 16) & 1u)) >> 16;
  return (u16)r;
}
__device__ __forceinline__ u32 pack2(float a, float b) {
  return (u32)f2bf(a) | ((u32)f2bf(b) << 16);
}
__device__ __forceinline__ float4 ldF4(const float* p) { return *(const float4*)p; }
__device__ __forceinline__ float fin(float v) { return isfinite(v) ? v : 0.f; }

// ---------------- K0: scalars ----------------
__global__ __launch_bounds__(256) void k0(const float* __restrict__ Araw,
                                          const float* __restrict__ logQ,
                                          const float* __restrict__ logR,
                                          float* hdr, float* Qd, float* Asc, u16* Ab16) {
  __shared__ __align__(16) float Bm[64 * PIT];
  __shared__ __align__(16) float red[256];
  __shared__ __align__(16) float vv[64];
  int tid = threadIdx.x;
  if (tid < 64) Qd[tid] = expf(logQ[tid]);
  float r = expf(logR[tid]);
  red[tid] = logf(r + 1e-4f);
  __syncthreads();
  for (int o = 128; o; o >>= 1) {
    if (tid < o) red[tid] += red[tid + o];
    __syncthreads();
  }
  if (tid == 0) hdr[2] = red[0];
  __syncthreads();
  float a0 = Araw[0];
  float okf = 1.0f;
  for (int u = 0; u < 16; ++u) {
    int idx = tid * 16 + u;
    int i = idx >> 6, j = idx & 63;
    float v = Araw[idx];
    bool good = (i == j) ? (v == a0) : (v == 0.0f);
    if (!good) okf = 0.0f;
  }
  red[tid] = okf;
  __syncthreads();
  for (int o = 128; o; o >>= 1) {
    if (tid < o) red[tid] = fminf(red[tid], red[tid + o]);
    __syncthreads();
  }
  float isDiag = red[0];
  __syncthreads();
  for (int u = 0; u < 16; ++u) {
    int idx = tid * 16 + u;
    int i = idx >> 6, j = idx & 63;
    float s = 0.f;
    for (int k = 0; k < 64; ++k) s += Araw[k * 64 + i] * Araw[k * 64 + j];
    Bm[i * PIT + j] = s;
  }
  __syncthreads();
  if (tid < 64) {
    vv[tid] = 1.0f;
    float lam = 0.f;
    for (int it = 0; it < 64; ++it) {
      float ui = 0.f;
      for (int k = 0; k < 64; ++k) ui += Bm[tid * PIT + k] * vv[k];
      float s = ui * ui;
      for (int o = 32; o; o >>= 1) s += __shfl_down(s, o);
      float n2 = __shfl(s, 0);
      float nr = sqrtf(fmaxf(n2, 1e-30f));
      vv[tid] = ui / nr;
      lam = nr;
    }
    if (tid == 0) red[0] = lam;
  }
  __syncthreads();
  float sig = sqrtf(fmaxf(red[0], 0.f));
  float scale = 0.98f / (sig + 1e-6f);
  if (tid == 0) {
    hdr[0] = scale * a0;
    hdr[1] = isDiag;
    hdr[3] = sig;
  }
  for (int u = 0; u < 16; ++u) {
    int idx = tid * 16 + u;
    float v = scale * Araw[idx];
    Asc[idx] = v;
    Ab16[idx] = f2bf(v);
  }
}

// ---------------- K1: per-t Woodbury precompute via MFMA (S and G only) ----
__global__ __launch_bounds__(512) void k1(const float* __restrict__ obs,
                                          const float* __restrict__ Lam,
                                          const float* __restrict__ logR,
                                          u16* __restrict__ Sg, u16* __restrict__ Gg,
                                          float* __restrict__ bv,
                                          float* __restrict__ cv, float* __restrict__ aNv) {
  int t = blockIdx.x, tid = threadIdx.x;
  __shared__ __align__(16) u16 Lt[64 * PL];
  __shared__ __align__(16) u16 LtW[64 * PL];
  __shared__ __align__(16) float w1a[NN], w2a[NN], wya[NN];
  __shared__ __align__(16) float red[512];
  int lane = tid & 63, wv = tid >> 6;
  int ln = lane & 15, q = lane >> 4;

  float cpart = 0.f, apart = 0.f;
  if (tid < NN) {
    float y = obs[(size_t)t * NN + tid];
    float r = expf(logR[tid]);
    float re = r + 1e-4f;
    float w1 = 1.0f / re;
    bool m = (y != y);
    w1a[tid] = w1;
    w2a[tid] = m ? 0.f : w1;
    wya[tid] = m ? 0.f : (w1 * y);
    cpart = m ? 0.f : (w1 * y * y);
    apart = m ? 0.f : 1.f;
  }
  const float4* Lsrc = (const float4*)(Lam + (size_t)t * NN * KKD);
  for (int u = 0; u < 8; ++u) {
    int fl = u * 512 + tid;
    float4 v = Lsrc[fl];
    int n = fl >> 4, k0 = (fl & 15) * 4;
    Lt[(k0 + 0) * PL + n] = f2bf(v.x);
    Lt[(k0 + 1) * PL + n] = f2bf(v.y);
    Lt[(k0 + 2) * PL + n] = f2bf(v.z);
    Lt[(k0 + 3) * PL + n] = f2bf(v.w);
  }
  __syncthreads();

  const float* Ws[2] = {w1a, w2a};
  u16* Os[2] = {Sg + (size_t)t * 4096, Gg + (size_t)t * 4096};
#pragma unroll
  for (int m = 0; m < 2; ++m) {
    const float* W = Ws[m];
    for (int u = 0; u < 4; ++u) {
      int fl = u * 512 + tid;
      int row = fl >> 5, c8 = (fl & 31) * 8;
      ushort4 lo = *(const ushort4*)&Lt[row * PL + c8];
      ushort4 hi = *(const ushort4*)&Lt[row * PL + c8 + 4];
      float4 wa = ldF4(&W[c8]);
      float4 wb = ldF4(&W[c8 + 4]);
      ushort4 olo, ohi;
      olo.x = f2bf(bf2f(lo.x) * wa.x); olo.y = f2bf(bf2f(lo.y) * wa.y);
      olo.z = f2bf(bf2f(lo.z) * wa.z); olo.w = f2bf(bf2f(lo.w) * wa.w);
      ohi.x = f2bf(bf2f(hi.x) * wb.x); ohi.y = f2bf(bf2f(hi.y) * wb.y);
      ohi.z = f2bf(bf2f(hi.z) * wb.z); ohi.w = f2bf(bf2f(hi.w) * wb.w);
      *(ushort4*)&LtW[row * PL + c8] = olo;
      *(ushort4*)&LtW[row * PL + c8 + 4] = ohi;
    }
    __syncthreads();
    u16* O = Os[m];
#pragma unroll
    for (int tl = 0; tl < 2; ++tl) {
      int td = wv + tl * 8, ti = td >> 2, tj = td & 3;
      f32x4 acc = {0.f, 0.f, 0.f, 0.f};
#pragma unroll
      for (int n0 = 0; n0 < 256; n0 += 32)
        acc = __builtin_amdgcn_mfma_f32_16x16x32_bf16(
            *(const short8*)&Lt[(ti * 16 + ln) * PL + n0 + q * 8],
            *(const short8*)&LtW[(tj * 16 + ln) * PL + n0 + q * 8], acc, 0, 0, 0);
      int col = tj * 16 + ln, rb = ti * 16 + q * 4;
#pragma unroll
      for (int r = 0; r < 4; ++r) O[(rb + r) * 64 + col] = f2bf(acc[r]);
    }
    __syncthreads();
  }

  {
    int k = tid >> 3, seg = tid & 7;
    float s = 0.f;
    for (int n = seg * 32; n < seg * 32 + 32; n += 4) {
      ushort4 l4 = *(const ushort4*)&Lt[k * PL + n];
      float4 wy = ldF4(&wya[n]);
      s += bf2f(l4.x) * wy.x + bf2f(l4.y) * wy.y + bf2f(l4.z) * wy.z + bf2f(l4.w) * wy.w;
    }
    red[tid] = s;
  }
  __syncthreads();
  if (tid < 64) {
    float acc = 0.f;
#pragma unroll
    for (int s = 0; s < 8; ++s) acc += red[tid * 8 + s];
    bv[(size_t)t * 64 + tid] = acc;
  }
  __syncthreads();
  red[tid] = cpart;
  __syncthreads();
  for (int o = 256; o; o >>= 1) {
    if (tid < o) red[tid] += red[tid + o];
    __syncthreads();
  }
  if (tid == 0) cv[t] = red[0];
  __syncthreads();
  red[tid] = apart;
  __syncthreads();
  for (int o = 256; o; o >>= 1) {
    if (tid < o) red[tid] += red[tid + o];
    __syncthreads();
  }
  if (tid == 0) aNv[t] = red[0];
}

// ---------------- MFMA fragment helpers (16x16x32 bf16) ----------------
__device__ __forceinline__ f32x4 mmLL(const u16* A, const u16* B, int ti, int tj,
                                      int ln, int q, f32x4 acc) {
  int ao = (ti * 16 + ln) * PB + q * 8;
  int bo = (tj * 16 + ln) * PB + q * 8;
#pragma unroll
  for (int k0 = 0; k0 < 64; k0 += 32)
    acc = __builtin_amdgcn_mfma_f32_16x16x32_bf16(*(const short8*)(A + ao + k0),
                                                  *(const short8*)(B + bo + k0), acc, 0, 0, 0);
  return acc;
}
__device__ __forceinline__ f32x4 mmLG(const u16* A, const u16* __restrict__ Bg, int ti,
                                      int tj, int ln, int q, f32x4 acc) {
  int ao = (ti * 16 + ln) * PB + q * 8;
  const u16* bp = Bg + (tj * 16 + ln) * 64 + q * 8;
#pragma unroll
  for (int k0 = 0; k0 < 64; k0 += 32)
    acc = __builtin_amdgcn_mfma_f32_16x16x32_bf16(*(const short8*)(A + ao + k0),
                                                  *(const short8*)(bp + k0), acc, 0, 0, 0);
  return acc;
}
__device__ __forceinline__ f32x4 mmGL(const u16* __restrict__ Ag, const u16* B, int ti,
                                      int tj, int ln, int q, f32x4 acc) {
  const u16* ap = Ag + (ti * 16 + ln) * 64 + q * 8;
  int bo = (tj * 16 + ln) * PB + q * 8;
#pragma unroll
  for (int k0 = 0; k0 < 64; k0 += 32)
    acc = __builtin_amdgcn_mfma_f32_16x16x32_bf16(*(const short8*)(ap + k0),
                                                  *(const short8*)(B + bo + k0), acc, 0, 0, 0);
  return acc;
}
__device__ __forceinline__ void stLDS(u16* Buf, int ti, int tj, int ln, int q, f32x4 v) {
  int col = tj * 16 + ln, rb = ti * 16 + q * 4;
#pragma unroll
  for (int r = 0; r < 4; ++r) Buf[(rb + r) * PB + col] = f2bf(v[r]);
}

// ---------------- K2a: warm-up sweep, GS-paired, Newton inverse -------------
// Per step: P_pred; M = I + P_pred*S; alpha via 3 power-iter matvecs;
// X = M^-1 via 9 Newton iters (X <- 2X - X*M*X, all MFMA bf16);
// P_upd = W = X * P_pred  (short-form update; no logdet needed here).
__global__ __launch_bounds__(512) void k2a(const u16* __restrict__ Sg,
                                           u16* __restrict__ Pout,
                                           const float* __restrict__ hdr,
                                           const float* __restrict__ Qd,
                                           const u16* __restrict__ Ab16) {
  int t0 = blockIdx.x * 2, tid = threadIdx.x;
  int lane = tid & 63, w = tid >> 6;
  int ln = lane & 15, q = lane >> 4;

  __shared__ __align__(16) u16 Pp16[64 * PB];  // P_prev / P_pred
  __shared__ __align__(16) u16 Mt[64 * PB];    // M^T bf16
  __shared__ __align__(16) u16 Xr[64 * PB];    // X row-major (also A*P temp)
  __shared__ __align__(16) u16 Xt[64 * PB];    // X transposed
  __shared__ __align__(16) u16 Ub[64 * PB];    // -U = -(X*M)
  __shared__ __align__(16) float pw[600];      // part[512] + v[72] + scalars

  float* part = pw;
  float* v = pw + 512;

  float aS = hdr[0];
  bool diag = (hdr[1] != 0.f);
  int row = tid >> 3, cg = tid & 7;

  for (int st = 0; st < 2; ++st) {
    int t = t0 + st;

    // ---- Phase A: P_pred -> Pp16 ----
    if (st == 0) {
      float pinit = (t == 0) ? 1.f : 0.15f;
      if (diag) {
        float a2 = aS * aS;
        float qr = Qd[row];
        uint4 o;
#pragma unroll
        for (int u = 0; u < 8; u += 2) {
          float va = ((cg * 8 + u == row) ? (a2 * pinit + qr) : 0.f);
          float vb = ((cg * 8 + u + 1 == row) ? (a2 * pinit + qr) : 0.f);
          ((u32*)&o)[u >> 1] = pack2(va, vb);
        }
        *(uint4*)&Pp16[row * PB + cg * 8] = o;
        __syncthreads();
      } else {
        uint4 o;
#pragma unroll
        for (int u = 0; u < 8; u += 2) {
          float va = (cg * 8 + u == row) ? pinit : 0.f;
          float vb = (cg * 8 + u + 1 == row) ? pinit : 0.f;
          ((u32*)&o)[u >> 1] = pack2(va, vb);
        }
        *(uint4*)&Pp16[row * PB + cg * 8] = o;
        __syncthreads();
#pragma unroll
        for (int tl = 0; tl < 2; ++tl) {
          int td = w + tl * 8, ti = td >> 2, tj = td & 3;
          f32x4 acc = {0.f, 0.f, 0.f, 0.f};
          acc = mmGL(Ab16, Pp16, ti, tj, ln, q, acc);
          stLDS(Xr, ti, tj, ln, q, acc);
        }
        __syncthreads();
#pragma unroll
        for (int tl = 0; tl < 2; ++tl) {
          int td = w + tl * 8, ti = td >> 2, tj = td & 3;
          f32x4 acc = {0.f, 0.f, 0.f, 0.f};
          acc = mmLG(Xr, Ab16, ti, tj, ln, q, acc);
          int col = tj * 16 + ln, rb = ti * 16 + q * 4;
#pragma unroll
          for (int r = 0; r < 4; ++r) {
            float vv = acc[r] + ((rb + r) == col ? Qd[rb + r] : 0.f);
            Pp16[(rb + r) * PB + col] = f2bf(vv);
          }
        }
        __syncthreads();
      }
    } else {
      // P_prev already in Pp16 (posterior of t-1)
      if (diag) {
        float a2 = aS * aS;
        float qr = Qd[row];
        uint4 raw = *(const uint4*)&Pp16[row * PB + cg * 8];
        float pv[8];
        pv[0] = bf2f((u16)(raw.x & 0xffff)); pv[1] = bf2f((u16)(raw.x >> 16));
        pv[2] = bf2f((u16)(raw.y & 0xffff)); pv[3] = bf2f((u16)(raw.y >> 16));
        pv[4] = bf2f((u16)(raw.z & 0xffff)); pv[5] = bf2f((u16)(raw.z >> 16));
        pv[6] = bf2f((u16)(raw.w & 0xffff)); pv[7] = bf2f((u16)(raw.w >> 16));
        uint4 o;
#pragma unroll
        for (int u = 0; u < 8; u += 2) {
          float va = a2 * pv[u] + ((cg * 8 + u == row) ? qr : 0.f);
          float vb = a2 * pv[u + 1] + ((cg * 8 + u + 1 == row) ? qr : 0.f);
          ((u32*)&o)[u >> 1] = pack2(va, vb);
        }
        *(uint4*)&Pp16[row * PB + cg * 8] = o;
        __syncthreads();
      } else {
#pragma unroll
        for (int tl = 0; tl < 2; ++tl) {
          int td = w + tl * 8, ti = td >> 2, tj = td & 3;
          f32x4 acc = {0.f, 0.f, 0.f, 0.f};
          acc = mmGL(Ab16, Pp16, ti, tj, ln, q, acc);
          stLDS(Xr, ti, tj, ln, q, acc);
        }
        __syncthreads();
#pragma unroll
        for (int tl = 0; tl < 2; ++tl) {
          int td = w + tl * 8, ti = td >> 2, tj = td & 3;
          f32x4 acc = {0.f, 0.f, 0.f, 0.f};
          acc = mmLG(Xr, Ab16, ti, tj, ln, q, acc);
          int col = tj * 16 + ln, rb = ti * 16 + q * 4;
#pragma unroll
          for (int r = 0; r < 4; ++r) {
            float vv = acc[r] + ((rb + r) == col ? Qd[rb + r] : 0.f);
            Pp16[(rb + r) * PB + col] = f2bf(vv);
          }
        }
        __syncthreads();
      }
    }

    // ---- Phase B: M = I + P_pred * S  -> Mt (transposed, bf16) ----
#pragma unroll
    for (int tl = 0; tl < 2; ++tl) {
      int td = w + tl * 8, ti = td >> 2, tj = td & 3;
      f32x4 acc = {0.f, 0.f, 0.f, 0.f};
      acc = mmLG(Pp16, Sg + (size_t)t * 4096, ti, tj, ln, q, acc);
      int col = tj * 16 + ln, rb = ti * 16 + q * 4;
      ushort4 o4;
      o4.x = f2bf(acc[0] + ((rb + 0) == col ? 1.f : 0.f));
      o4.y = f2bf(acc[1] + ((rb + 1) == col ? 1.f : 0.f));
      o4.z = f2bf(acc[2] + ((rb + 2) == col ? 1.f : 0.f));
      o4.w = f2bf(acc[3] + ((rb + 3) == col ? 1.f : 0.f));
      *(ushort4*)&Mt[col * PB + rb] = o4;  // transposed store
    }
    if (tid < 64) v[tid] = 1.f;
    __syncthreads();

    // ---- Power iteration: 3 matvecs, lambda_est = max3/max2 ----
    float mx[3];
    for (int itp = 0; itp < 3; ++itp) {
      int i = tid & 63, seg = tid >> 6;
      float s = 0.f;
#pragma unroll
      for (int u = 0; u < 8; ++u) {
        int k = seg * 8 + u;
        s += bf2f(Mt[k * PB + i]) * v[k];
      }
      part[tid] = s;
      __syncthreads();
      if (tid < 64) {
        float acc = 0.f;
#pragma unroll
        for (int sg = 0; sg < 8; ++sg) acc += part[tid + 64 * sg];
        v[tid] = acc;
        float m = fabsf(acc);
        for (int o = 32; o; o >>= 1) m = fmaxf(m, __shfl_down(m, o));
        if (tid == 0) pw[584 + itp] = m;
      }
      __syncthreads();
      mx[itp] = pw[584 + itp];
    }
    float lam = mx[2] / fmaxf(mx[1], 1e-20f);
    if (!isfinite(lam) || lam < 1.0f || lam > 1e4f) lam = 64.f;
    float alpha = 1.0f / (lam * 1.02f);

    // ---- Newton: X0 = alpha*I; X <- 2X - X*M*X (9 iters) ----
    f32x4 Xreg[2];
#pragma unroll
    for (int tl = 0; tl < 2; ++tl) {
      int td = w + tl * 8, ti = td >> 2, tj = td & 3;
      int col = tj * 16 + ln, rb = ti * 16 + q * 4;
      ushort4 o4;
#pragma unroll
      for (int r = 0; r < 4; ++r) {
        float xv = ((rb + r) == col) ? alpha : 0.f;
        Xreg[tl][r] = xv;
        Xr[(rb + r) * PB + col] = f2bf(xv);
      }
      o4.x = f2bf(Xreg[tl][0]); o4.y = f2bf(Xreg[tl][1]);
      o4.z = f2bf(Xreg[tl][2]); o4.w = f2bf(Xreg[tl][3]);
      *(ushort4*)&Xt[col * PB + rb] = o4;
    }
    __syncthreads();

    for (int it = 0; it < 9; ++it) {
      // U = X*M  (C = Xr · Mt^T);  store -U row-major
#pragma unroll
      for (int tl = 0; tl < 2; ++tl) {
        int td = w + tl * 8, ti = td >> 2, tj = td & 3;
        f32x4 u = {0.f, 0.f, 0.f, 0.f};
        u = mmLL(Xr, Mt, ti, tj, ln, q, u);
        int col = tj * 16 + ln, rb = ti * 16 + q * 4;
#pragma unroll
        for (int r = 0; r < 4; ++r) Ub[(rb + r) * PB + col] = f2bf(-u[r]);
      }
      __syncthreads();
      // X_new = 2X + (-U)*X
#pragma unroll
      for (int tl = 0; tl < 2; ++tl) {
        int td = w + tl * 8, ti = td >> 2, tj = td & 3;
        f32x4 acc;
#pragma unroll
        for (int r = 0; r < 4; ++r) acc[r] = 2.f * Xreg[tl][r];
        acc = mmLL(Ub, Xt, ti, tj, ln, q, acc);
        Xreg[tl] = acc;
        int col = tj * 16 + ln, rb = ti * 16 + q * 4;
        ushort4 o4;
#pragma unroll
        for (int r = 0; r < 4; ++r) {
          u16 h = f2bf(acc[r]);
          Xr[(rb + r) * PB + col] = h;
          ((u16*)&o4)[r] = h;
        }
        *(ushort4*)&Xt[col * PB + rb] = o4;
      }
      __syncthreads();
    }

    // ---- W = X * P_pred  (= P_upd, short form) ----
    f32x4 pacc[2];
#pragma unroll
    for (int tl = 0; tl < 2; ++tl) {
      int td = w + tl * 8, ti = td >> 2, tj = td & 3;
      f32x4 acc = {0.f, 0.f, 0.f, 0.f};
      acc = mmLL(Xr, Pp16, ti, tj, ln, q, acc);
      pacc[tl] = acc;
      int col = tj * 16 + ln, rb = ti * 16 + q * 4;
#pragma unroll
      for (int r = 0; r < 4; ++r)
        Pout[(size_t)t * 4096 + (rb + r) * 64 + col] = f2bf(fin(acc[r]));
    }
    if (st == 0) {
      __syncthreads();
#pragma unroll
      for (int tl = 0; tl < 2; ++tl) {
        int td = w + tl * 8, ti = td >> 2, tj = td & 3;
        int col = tj * 16 + ln, rb = ti * 16 + q * 4;
#pragma unroll
        for (int r = 0; r < 4; ++r)
          Pp16[(rb + r) * PB + col] = f2bf(fin(pacc[tl][r]));
      }
      __syncthreads();
    }
  }
}

// ---------------- K2b: final sweep — exact GJ, W + logdet only -------------
__global__ __launch_bounds__(512) void k2b(const u16* __restrict__ Sg,
                                           const u16* __restrict__ Pin,
                                           u16* __restrict__ Wout,
                                           float* __restrict__ ldv,
                                           const float* __restrict__ hdr,
                                           const float* __restrict__ Qd,
                                           const u16* __restrict__ Ab16) {
  int t = blockIdx.x, tid = threadIdx.x;
  int lane = tid & 63, w = tid >> 6;
  int ln = lane & 15, q = lane >> 4;
  int ig = tid >> 4, jg = tid & 15, i0 = 2 * ig, j0 = 4 * jg;

  __shared__ __align__(16) u16 Pp16[64 * PB];
  __shared__ __align__(16) float M32[64 * PIT];
  __shared__ __align__(16) u16 XYb[64 * PB];

  float aS = hdr[0];
  bool diag = (hdr[1] != 0.f);
  int row = tid >> 3, cg = tid & 7;

  // ---- Phase A: P_pred -> Pp16 ----
  float pv[8];
  if (t == 0) {
#pragma unroll
    for (int u = 0; u < 8; ++u) pv[u] = (cg * 8 + u == row) ? 1.f : 0.f;
  } else {
    uint4 raw = *(const uint4*)(Pin + (size_t)(t - 1) * 4096 + tid * 8);
    pv[0] = bf2f((u16)(raw.x & 0xffff)); pv[1] = bf2f((u16)(raw.x >> 16));
    pv[2] = bf2f((u16)(raw.y & 0xffff)); pv[3] = bf2f((u16)(raw.y >> 16));
    pv[4] = bf2f((u16)(raw.z & 0xffff)); pv[5] = bf2f((u16)(raw.z >> 16));
    pv[6] = bf2f((u16)(raw.w & 0xffff)); pv[7] = bf2f((u16)(raw.w >> 16));
  }
  if (diag) {
    float a2 = aS * aS;
    float qr = Qd[row];
    uint4 o;
#pragma unroll
    for (int u = 0; u < 8; u += 2) {
      float va = a2 * pv[u] + ((cg * 8 + u == row) ? qr : 0.f);
      float vb = a2 * pv[u + 1] + ((cg * 8 + u + 1 == row) ? qr : 0.f);
      ((u32*)&o)[u >> 1] = pack2(va, vb);
    }
    *(uint4*)&Pp16[row * PB + cg * 8] = o;
  } else {
    uint4 o;
    o.x = pack2(pv[0], pv[1]); o.y = pack2(pv[2], pv[3]);
    o.z = pack2(pv[4], pv[5]); o.w = pack2(pv[6], pv[7]);
    *(uint4*)&Pp16[row * PB + cg * 8] = o;
    __syncthreads();
#pragma unroll
    for (int tl = 0; tl < 2; ++tl) {
      int td = w + tl * 8, ti = td >> 2, tj = td & 3;
      f32x4 acc = {0.f, 0.f, 0.f, 0.f};
      acc = mmGL(Ab16, Pp16, ti, tj, ln, q, acc);
      stLDS(XYb, ti, tj, ln, q, acc);
    }
    __syncthreads();
#pragma unroll
    for (int tl = 0; tl < 2; ++tl) {
      int td = w + tl * 8, ti = td >> 2, tj = td & 3;
      f32x4 acc = {0.f, 0.f, 0.f, 0.f};
      acc = mmLG(XYb, Ab16, ti, tj, ln, q, acc);
      int col = tj * 16 + ln, rb = ti * 16 + q * 4;
#pragma unroll
      for (int r = 0; r < 4; ++r) {
        float vv = acc[r] + ((rb + r) == col ? Qd[rb + r] : 0.f);
        Pp16[(rb + r) * PB + col] = f2bf(vv);
      }
    }
  }
  __syncthreads();

  // ---- Phase B: M = I + P_pred * S ----
#pragma unroll
  for (int tl = 0; tl < 2; ++tl) {
    int td = w + tl * 8, ti = td >> 2, tj = td & 3;
    f32x4 acc = {0.f, 0.f, 0.f, 0.f};
    acc = mmLG(Pp16, Sg + (size_t)t * 4096, ti, tj, ln, q, acc);
    int col = tj * 16 + ln, rb = ti * 16 + q * 4;
#pragma unroll
    for (int r = 0; r < 4; ++r) M32[(rb + r) * PIT + col] = acc[r] + ((rb + r) == col ? 1.f : 0.f);
  }
  __syncthreads();

  // ---- Phase C: register-resident Gauss-Jordan + logdet ----
  float r0[4], r1[4];
  {
    float4 a = ldF4(&M32[i0 * PIT + j0]);
    float4 b = ldF4(&M32[(i0 + 1) * PIT + j0]);
    r0[0] = a.x; r0[1] = a.y; r0[2] = a.z; r0[3] = a.w;
    r1[0] = b.x; r1[1] = b.y; r1[2] = b.z; r1[3] = b.w;
  }
  float ldacc = 0.f;
  int provBase = lane & 48;
  for (int g = 0; g < 16; ++g) {
#pragma unroll
    for (int u = 0; u < 4; ++u) {
      int j = g * 4 + u;
      float4 pq = ldF4(&M32[j * PIT + j0]);
      float pr4[4] = {pq.x, pq.y, pq.z, pq.w};
      float piv = __shfl(pr4[u], g);
      float f0 = __shfl(r0[u], provBase + g);
      float f1 = __shfl(r1[u], provBase + g);
      float ap = fabsf(piv);
      float pvv = (ap < 1e-12f) ? ((piv < 0.f) ? -1e-12f : 1e-12f) : piv;
      float prc = 1.0f / pvv;
      if (tid == 0) ldacc += logf(fabsf(pvv));
      float fp0 = f0 * prc, fp1 = f1 * prc;
#pragma unroll
      for (int c = 0; c < 4; ++c) {
        r0[c] = fmaf(-fp0, pr4[c], r0[c]);
        r1[c] = fmaf(-fp1, pr4[c], r1[c]);
      }
      if (jg == g) { r0[u] = -fp0; r1[u] = -fp1; }
      int jrow = 2 * g + (u >> 1);
      if (ig == jrow) {
        if ((u & 1) == 0) {
#pragma unroll
          for (int c = 0; c < 4; ++c) r0[c] = pr4[c] * prc;
          if (jg == g) r0[u] = prc;
        } else {
#pragma unroll
          for (int c = 0; c < 4; ++c) r1[c] = pr4[c] * prc;
          if (jg == g) r1[u] = prc;
        }
      }
      if (j < 63) {
        int jn = j + 1;
        if (i0 == jn)
          *(float4*)&M32[jn * PIT + j0] = make_float4(r0[0], r0[1], r0[2], r0[3]);
        else if (i0 + 1 == jn)
          *(float4*)&M32[jn * PIT + j0] = make_float4(r1[0], r1[1], r1[2], r1[3]);
      }
      __syncthreads();
    }
  }

  // ---- Phase D: pack inverse regs -> XYb (bf16) ----
  {
    ushort4 oa, ob;
    oa.x = f2bf(r0[0]); oa.y = f2bf(r0[1]); oa.z = f2bf(r0[2]); oa.w = f2bf(r0[3]);
    ob.x = f2bf(r1[0]); ob.y = f2bf(r1[1]); ob.z = f2bf(r1[2]); ob.w = f2bf(r1[3]);
    *(ushort4*)&XYb[i0 * PB + j0] = oa;
    *(ushort4*)&XYb[(i0 + 1) * PB + j0] = ob;
  }
  __syncthreads();

  // ---- Phase E: W = X * P_pred -> Wout ----
#pragma unroll
  for (int tl = 0; tl < 2; ++tl) {
    int td = w + tl * 8, ti = td >> 2, tj = td & 3;
    f32x4 acc = {0.f, 0.f, 0.f, 0.f};
    acc = mmLL(XYb, Pp16, ti, tj, ln, q, acc);
    int col = tj * 16 + ln, rb = ti * 16 + q * 4;
#pragma unroll
    for (int r = 0; r < 4; ++r)
      Wout[(size_t)t * 4096 + (rb + r) * 64 + col] = f2bf(fin(acc[r]));
  }
  if (tid == 0) ldv[t] = fin(ldacc);
}

// ---------------- K3: state + loglik, chunked parallel with warmup ----------
#define OWN 4
#define WARM 12
__global__ __launch_bounds__(256) void k3(const u16* __restrict__ Gg, const u16* __restrict__ Wg,
                                          const float* __restrict__ bv, const float* __restrict__ cv,
                                          const float* __restrict__ aNv, const float* __restrict__ ldv,
                                          const float* __restrict__ hdr, const float* __restrict__ Asc,
                                          float* __restrict__ out) {
  int b = blockIdx.x, tid = threadIdx.x;
  int t0 = b * OWN;
  int tw = t0 - WARM;
  if (tw < 0) tw = 0;
  __shared__ __align__(16) float z[64], zp[64], q[64], wv[64], uu[64], part[256];
  float aS = hdr[0];
  bool diag = (hdr[1] != 0.f);
  float slr = hdr[2];
  if (tid < 64) z[tid] = 0.f;
  __syncthreads();
  for (int t = tw; t < t0 + OWN; ++t) {
    bool own = (t >= t0);
    if (tid < 64) {
      if (diag)
        zp[tid] = aS * z[tid];
      else {
        float s = 0.f;
        for (int k = 0; k < 64; k += 4) {
          float4 a = ldF4(&Asc[tid * 64 + k]);
          s += a.x * z[k] + a.y * z[k + 1] + a.z * z[k + 2] + a.w * z[k + 3];
        }
        zp[tid] = s;
      }
    }
    __syncthreads();
    {
      int i = tid & 63, seg = tid >> 6;
      const u16* Gr = Gg + (size_t)t * 4096 + i * 64 + seg * 16;
      float s = 0.f;
      for (int u = 0; u < 16; u += 4) {
        ushort4 g4 = *(const ushort4*)(Gr + u);
        const float* zz = &zp[seg * 16 + u];
        s += bf2f(g4.x) * zz[0] + bf2f(g4.y) * zz[1] + bf2f(g4.z) * zz[2] + bf2f(g4.w) * zz[3];
      }
      part[tid] = s;
    }
    __syncthreads();
    if (tid < 64) {
      float qi = part[tid] + part[tid + 64] + part[tid + 128] + part[tid + 192];
      q[tid] = qi;
      wv[tid] = bv[(size_t)t * 64 + tid] - qi;
    }
    __syncthreads();
    {
      int i = tid & 63, seg = tid >> 6;
      const u16* Wr = Wg + (size_t)t * 4096 + i * 64 + seg * 16;
      float s = 0.f;
      for (int u = 0; u < 16; u += 4) {
        ushort4 g4 = *(const ushort4*)(Wr + u);
        const float* zz = &wv[seg * 16 + u];
        s += bf2f(g4.x) * zz[0] + bf2f(g4.y) * zz[1] + bf2f(g4.z) * zz[2] + bf2f(g4.w) * zz[3];
      }
      part[tid] = s;
    }
    __syncthreads();
    if (tid < 64) {
      float ui = part[tid] + part[tid + 64] + part[tid + 128] + part[tid + 192];
      uu[tid] = ui;
      float zi = zp[tid] + ui;
      z[tid] = isfinite(zi) ? zi : 0.f;
    }
    __syncthreads();
    if (tid < 64) {
      float bz = bv[(size_t)t * 64 + tid] * zp[tid];
      float zq = zp[tid] * q[tid];
      float wu = wv[tid] * uu[tid];
      for (int o = 32; o; o >>= 1) {
        bz += __shfl_down(bz, o);
        zq += __shfl_down(zq, o);
        wu += __shfl_down(wu, o);
      }
      if (tid == 0 && own) {
        float mahal = cv[t] - 2.f * bz + zq - wu;
        float ll = -0.5f * (aNv[t] * LOG2PI + slr + ldv[t] + mahal);
        if (!isfinite(ll)) ll = -1e6f;
        out[(size_t)t * 65 + 64] = ll;
      }
      if (own) out[(size_t)t * 65 + tid] = z[tid];
    }
    __syncthreads();
  }
}

extern "C" void kernel_launch(void* const* d_in, const int* in_sizes, int n_in,
                              void* d_out, int out_size, void* d_ws, size_t ws_size,
                              hipStream_t stream) {
  const float* obs = (const float*)d_in[0];
  const float* Lam = (const float*)d_in[1];
  const float* Araw = (const float*)d_in[2];
  const float* logQ = (const float*)d_in[3];
  const float* logR = (const float*)d_in[4];
  float* out = (float*)d_out;

  char* w = (char*)d_ws;
  float* hdr = (float*)w;
  float* Qd = hdr + 64;
  float* Asc = hdr + 128;
  u16* Ab16 = (u16*)(hdr + 4224);
  const size_t MB = (size_t)TT * 4096;
  u16* Sg = (u16*)(w + 32768);
  u16* Gg = Sg + MB;
  u16* Wg = Gg + MB;
  u16* Pb0 = Wg + MB;
  float* bv = (float*)(Pb0 + MB);
  float* cv = bv + (size_t)TT * 64;
  float* aNv = cv + TT;
  float* ldv = aNv + TT;

  k0<<<dim3(1), dim3(256), 0, stream>>>(Araw, logQ, logR, hdr, Qd, Asc, Ab16);
  k1<<<dim3(TT), dim3(512), 0, stream>>>(obs, Lam, logR, Sg, Gg, bv, cv, aNv);
  k2a<<<dim3(TT / 2), dim3(512), 0, stream>>>(Sg, Pb0, hdr, Qd, Ab16);
  k2b<<<dim3(TT), dim3(512), 0, stream>>>(Sg, Pb0, Wg, ldv, hdr, Qd, Ab16);
  k3<<<dim3(TT / OWN), dim3(256), 0, stream>>>(Gg, Wg, bv, cv, aNv, ldv, hdr, Asc, out);
}